// Round 14
// baseline (13405.972 us; speedup 1.0000x reference)
//
#include <hip/hip_runtime.h>
#include <hip/hip_bf16.h>
#include <stdint.h>

// LSTM B=64 S=1024 D=1024 H=1024, gates f,i,o,g all sigmoid.
// Phase 1: xproj = x@W + bW + bU  (bf16 MFMA GEMM)
// Phase 2: persistent recurrent kernel, 128 WGs = 4 batch-groups x 32 col-WGs.
//   R14: TAGGED-UNIT dataflow. h is published as 8B atomic words [2xbf16 | step tag].
//   No flags, no producer vmcnt drain, no separate poll: the consumer's data load IS
//   the availability check (retry until tag==s). Depth-2 parity + consume-all makes
//   overwrites safe (inductive argument, enforced per-unit by tags). One barrier/step.

typedef __attribute__((ext_vector_type(8))) short short8;
typedef __attribute__((ext_vector_type(4))) float floatx4;
typedef __attribute__((ext_vector_type(2))) float floatx2;

__device__ __forceinline__ unsigned short f2bf(float x){
  union { float f; unsigned int u; } v; v.f = x;
  unsigned int r = v.u + 0x7fffu + ((v.u >> 16) & 1u);
  return (unsigned short)(r >> 16);
}
__device__ __forceinline__ float bf2f(unsigned short b){
  union { unsigned int u; float f; } v; v.u = ((unsigned int)b) << 16; return v.f;
}
__device__ __forceinline__ float fsigmoid(float x){ return 1.0f / (1.0f + __expf(-x)); }
__device__ __forceinline__ float ftanh(float x){ return 1.0f - 2.0f / (1.0f + __expf(2.0f * x)); }

// ---- transpose [g][d][h] fp32 -> [g][h][d] bf16 (per-gate 1024x1024) ----
__global__ void k_transpose_bf16(const float* __restrict__ src, unsigned short* __restrict__ dst){
  __shared__ float tile[64][65];
  const int g  = blockIdx.z;
  const int d0 = blockIdx.x * 64;
  const int h0 = blockIdx.y * 64;
  const int t  = threadIdx.x;
  const float* s    = src + ((size_t)g << 20);
  unsigned short* o = dst + ((size_t)g << 20);
  #pragma unroll
  for (int i = 0; i < 16; i++){
    int e = i * 256 + t;
    int r = e >> 6, c = e & 63;
    tile[r][c] = s[(size_t)(d0 + r) * 1024 + (h0 + c)];
  }
  __syncthreads();
  #pragma unroll
  for (int i = 0; i < 16; i++){
    int e = i * 256 + t;
    int a = e >> 6, bb = e & 63;
    o[(size_t)(h0 + a) * 1024 + (d0 + bb)] = f2bf(tile[bb][a]);
  }
}

// ---- convert input chunk (B,S,D) fp32 -> Abuf[(sl*64+b)][d] bf16 ----
__global__ void k_convert_x(const float* __restrict__ inp, unsigned short* __restrict__ abuf, int s0){
  int idx = blockIdx.x * 256 + threadIdx.x;
  int e = idx * 4;
  int r = e >> 10, d = e & 1023;
  int b = r & 63, sl = r >> 6;
  floatx4 v = *(const floatx4*)(inp + ((size_t)(b * 1024 + (s0 + sl)) * 1024 + d));
  unsigned long long pk = (unsigned long long)f2bf(v[0])
                        | ((unsigned long long)f2bf(v[1]) << 16)
                        | ((unsigned long long)f2bf(v[2]) << 32)
                        | ((unsigned long long)f2bf(v[3]) << 48);
  *(unsigned long long*)(abuf + (size_t)r * 1024 + d) = pk;
}

// ---- xproj GEMM: C[M][4096] = A[M][1024] @ Bt^T + (bW+bU), bf16 out ----
__global__ void __launch_bounds__(256) k_gemm_xproj(
    const unsigned short* __restrict__ A,
    const unsigned short* __restrict__ Bt,
    const float* __restrict__ bW,
    const float* __restrict__ bU,
    unsigned short* __restrict__ Cc)
{
  __shared__ unsigned short As[2][128][64];
  __shared__ unsigned short Bs[2][128][64];
  const int t = threadIdx.x;
  const int w = t >> 6;
  const int lane = t & 63;
  const int m0 = blockIdx.x * 128;
  const int n0 = blockIdx.y * 128;
  floatx4 acc[4][4];
  #pragma unroll
  for (int i = 0; i < 4; i++)
    #pragma unroll
    for (int j = 0; j < 4; j++)
      acc[i][j] = (floatx4){0.f, 0.f, 0.f, 0.f};

  auto stage = [&](int bufi, int kt){
    #pragma unroll
    for (int i = 0; i < 4; i++){
      int chunk = i * 256 + t;
      int r = chunk >> 3, j = chunk & 7;
      int js = j ^ (r & 7);
      __builtin_amdgcn_global_load_lds(
        (const __attribute__((address_space(1))) unsigned int*)(A + (size_t)(m0 + r) * 1024 + kt * 64 + js * 8),
        (__attribute__((address_space(3))) unsigned int*)(&As[bufi][0][0] + (i * 256 + w * 64) * 8), 16, 0, 0);
    }
    #pragma unroll
    for (int i = 0; i < 4; i++){
      int chunk = i * 256 + t;
      int r = chunk >> 3, j = chunk & 7;
      int js = j ^ (r & 7);
      __builtin_amdgcn_global_load_lds(
        (const __attribute__((address_space(1))) unsigned int*)(Bt + (size_t)(n0 + r) * 1024 + kt * 64 + js * 8),
        (__attribute__((address_space(3))) unsigned int*)(&Bs[bufi][0][0] + (i * 256 + w * 64) * 8), 16, 0, 0);
    }
  };

  auto compute = [&](int bufi){
    const int mi0 = (w >> 1) * 64;
    const int ni0 = (w & 1) * 64;
    #pragma unroll
    for (int kc = 0; kc < 2; kc++){
      short8 af[4], bfr[4];
      #pragma unroll
      for (int mi = 0; mi < 4; mi++){
        int row = mi0 + mi * 16 + (lane & 15);
        int j = kc * 4 + (lane >> 4);
        af[mi] = *(const short8*)&As[bufi][row][(j ^ (row & 7)) * 8];
      }
      #pragma unroll
      for (int ni = 0; ni < 4; ni++){
        int row = ni0 + ni * 16 + (lane & 15);
        int j = kc * 4 + (lane >> 4);
        bfr[ni] = *(const short8*)&Bs[bufi][row][(j ^ (row & 7)) * 8];
      }
      #pragma unroll
      for (int mi = 0; mi < 4; mi++)
        #pragma unroll
        for (int ni = 0; ni < 4; ni++)
          acc[mi][ni] = __builtin_amdgcn_mfma_f32_16x16x32_bf16(af[mi], bfr[ni], acc[mi][ni], 0, 0, 0);
    }
  };

  stage(0, 0);
  int buf = 0;
  for (int kt = 0; kt < 16; kt++){
    __syncthreads();
    if (kt < 15) stage(buf ^ 1, kt + 1);
    compute(buf);
    buf ^= 1;
  }

  {
    const int mi0 = (w >> 1) * 64;
    const int ni0 = (w & 1) * 64;
    #pragma unroll
    for (int ni = 0; ni < 4; ni++){
      int col = n0 + ni0 + ni * 16 + (lane & 15);
      float bias = bW[col] + bU[col];
      #pragma unroll
      for (int mi = 0; mi < 4; mi++){
        int mrow = m0 + mi0 + mi * 16 + (lane >> 4) * 4;
        #pragma unroll
        for (int r = 0; r < 4; r++)
          Cc[(size_t)(mrow + r) * 4096 + col] = f2bf(acc[mi][ni][r] + bias);
      }
    }
  }
}

// ---- persistent recurrent kernel: 128 WGs = 4 groups(16 batches) x 32 col-WGs ----
// Group buffer (per parity, per group): 64KB = 32 subtiles x 2KB. Subtile kc holds the
// MFMA A-frag for k in [kc*32,kc*32+32) as TAGGED 8B units:
//   unit u = (jj*16 + r)*4 + q  at byte u*8, holding [lo32 = bf16(k=kc*32+jj*8+2q),
//   bf16(k=..+2q+1) | hi32 = tag]. Tag of h-state consumed at step s is s (h0: tag 0
//   from memset). Consumer lane l reads units (l*4)..(l*4+3) (contiguous 32B) of each
//   subtile via 8B agent atomic loads; retries until all tags==s. Producer thread
//   (b,cc2) publishes ONE 8B atomic store [h pair | s+1]. No flags, no drains.
__global__ void __launch_bounds__(256, 1) k_lstm_rec(
    const unsigned short* __restrict__ xp,   // [SC*64][4096] bf16
    const unsigned short* __restrict__ Ut,   // [4096][1024] bf16 (gate-major rows)
    unsigned long long* hbs,                 // [2][4][65536B] tagged h group buffers
    float* cstate,                           // [64][1024]
    float* __restrict__ out,                 // (B,S,H) fp32
    float* __restrict__ hlast,
    float* __restrict__ clast,
    int s_base, int SC)
{
  const int t = threadIdx.x;
  const int w = t >> 6;            // wave = gate
  const int lane = t & 63;
  const int wgid = blockIdx.x;
  const int g  = wgid & 3;         // batch group: batches 16g..16g+15
  const int j  = wgid >> 2;        // col-slice: h-cols [j*32, j*32+32)
  const int B0 = g * 16;
  const int gc0 = j * 32;

  __shared__ float glds[2][4][16][33];       // parity-double-buffered gate exchange

  // U in VGPRs/AGPRs: wave w = gate w, cols gc0..gc0+31, full K=1024.
  short8 bfrag0[32], bfrag1[32];
  {
    const unsigned short* bp0 = Ut + (size_t)(w * 1024 + gc0 + (lane & 15)) * 1024 + (lane >> 4) * 8;
    const unsigned short* bp1 = bp0 + (size_t)16 * 1024;
    #pragma unroll
    for (int kc = 0; kc < 32; kc++){
      bfrag0[kc] = *(const short8*)(bp0 + kc * 32);
      bfrag1[kc] = *(const short8*)(bp1 + kc * 32);
    }
  }

  const int b   = t >> 4;          // local batch 0..15 owned in epilogue
  const int cc2 = (t & 15) * 2;    // 2 local h-cols owned: cc2, cc2+1
  floatx2 cst;
  if (s_base == 0) cst = (floatx2){0.f, 0.f};
  else             cst = *(const floatx2*)&cstate[(size_t)(B0 + b) * 1024 + gc0 + cc2];

  int bail = 20000000;

  for (int sl = 0; sl < SC; sl++){
    const int s = s_base + sl;
    const int p = s & 1;

    // xp prefetch (independent of h): 2 cols per gate as one 4B load
    unsigned int xu[4];
    {
      const unsigned short* xr = xp + ((size_t)(sl * 64 + B0 + b)) * 4096 + gc0 + cc2;
      #pragma unroll
      for (int gg = 0; gg < 4; gg++) xu[gg] = *(const unsigned int*)(xr + gg * 1024);
    }
    __builtin_amdgcn_sched_barrier(0);

    const char* gsrc = (const char*)hbs + ((size_t)p * 4 + g) * 65536;
    floatx4 acc0 = (floatx4){0.f,0.f,0.f,0.f};
    floatx4 acc1 = (floatx4){0.f,0.f,0.f,0.f};

    unsigned long long uA[8][4], uB[8][4];
    auto issue8 = [&](unsigned long long (&u)[8][4], int ch){
      #pragma unroll
      for (int i = 0; i < 8; i++){
        const unsigned long long* sp2 = (const unsigned long long*)(gsrc + (ch * 8 + i) * 2048 + lane * 32);
        #pragma unroll
        for (int q = 0; q < 4; q++)
          u[i][q] = __hip_atomic_load(sp2 + q, __ATOMIC_RELAXED, __HIP_MEMORY_SCOPE_AGENT);
      }
    };
    auto verify8 = [&](unsigned long long (&u)[8][4], int ch){
      while (true){
        bool ok = true;
        #pragma unroll
        for (int i = 0; i < 8; i++)
          #pragma unroll
          for (int q = 0; q < 4; q++)
            ok &= ((unsigned)(u[i][q] >> 32) == (unsigned)s);
        if (__all(ok)) break;
        __builtin_amdgcn_s_sleep(1);
        if (--bail < 0) break;
        issue8(u, ch);                       // reload stale chunk
      }
    };
    auto crunch8 = [&](unsigned long long (&u)[8][4], int ch){
      #pragma unroll
      for (int i = 0; i < 8; i++){
        union { unsigned int wrd[4]; short8 v; } cu;
        #pragma unroll
        for (int q = 0; q < 4; q++) cu.wrd[q] = (unsigned int)u[i][q];
        acc0 = __builtin_amdgcn_mfma_f32_16x16x32_bf16(cu.v, bfrag0[ch * 8 + i], acc0, 0, 0, 0);
        acc1 = __builtin_amdgcn_mfma_f32_16x16x32_bf16(cu.v, bfrag1[ch * 8 + i], acc1, 0, 0, 0);
      }
    };

    issue8(uA, 0);
    issue8(uB, 1);
    verify8(uA, 0);
    crunch8(uA, 0);
    issue8(uA, 2);
    verify8(uB, 1);
    crunch8(uB, 1);
    issue8(uB, 3);
    verify8(uA, 2);
    crunch8(uA, 2);
    verify8(uB, 3);
    crunch8(uB, 3);

    // publish gate values into parity glds. C: row=(l>>4)*4+reg, col=l&15.
    {
      const int r0 = (lane >> 4) * 4;
      const int cl = lane & 15;
      #pragma unroll
      for (int r = 0; r < 4; r++){
        glds[p][w][r0 + r][cl]      = acc0[r];
        glds[p][w][r0 + r][16 + cl] = acc1[r];
      }
    }
    __syncthreads();                                    // only barrier per step

    // epilogue: thread owns (b, cc2) and (b, cc2+1)
    float hout[2];
    #pragma unroll
    for (int d = 0; d < 2; d++){
      float fv = fsigmoid(glds[p][0][b][cc2 + d] + bf2f((unsigned short)(xu[0] >> (16 * d))));
      float iv = fsigmoid(glds[p][1][b][cc2 + d] + bf2f((unsigned short)(xu[1] >> (16 * d))));
      float ov = fsigmoid(glds[p][2][b][cc2 + d] + bf2f((unsigned short)(xu[2] >> (16 * d))));
      float gv = fsigmoid(glds[p][3][b][cc2 + d] + bf2f((unsigned short)(xu[3] >> (16 * d))));  // sigmoid, not tanh
      float cv = fv * cst[d] + iv * gv;
      cst[d] = cv;
      hout[d] = ov * ftanh(cv);
    }

    // publish h: ONE 8B atomic store [2xbf16 | tag s+1] - fire and forget.
    {
      unsigned long long pv = (unsigned long long)((unsigned int)f2bf(hout[0])
                             | ((unsigned int)f2bf(hout[1]) << 16))
                             | ((unsigned long long)(unsigned int)(s + 1) << 32);
      unsigned long long* dst = (unsigned long long*)((char*)hbs
                + ((size_t)(p ^ 1) * 4 + g) * 65536 + j * 2048
                + ((((cc2 >> 3) * 16 + b) * 4 + ((cc2 & 7) >> 1)) << 3));
      __hip_atomic_store(dst, pv, __ATOMIC_RELAXED, __HIP_MEMORY_SCOPE_AGENT);
    }

    if (s == 1023){
      *(floatx2*)&hlast[(size_t)(B0 + b) * 1024 + gc0 + cc2] = (floatx2){hout[0], hout[1]};
      *(floatx2*)&clast[(size_t)(B0 + b) * 1024 + gc0 + cc2] = cst;
    }

    // out store off the critical path (no drain - kernel end / in-order retirement)
    *(floatx2*)&out[((size_t)(B0 + b) * 1024 + s) * 1024 + gc0 + cc2] = (floatx2){hout[0], hout[1]};
  }

  *(floatx2*)&cstate[(size_t)(B0 + b) * 1024 + gc0 + cc2] = cst;
}

extern "C" void kernel_launch(void* const* d_in, const int* in_sizes, int n_in,
                              void* d_out, int out_size, void* d_ws, size_t ws_size,
                              hipStream_t stream)
{
  (void)in_sizes; (void)n_in; (void)out_size;
  const float* input_emb = (const float*)d_in[0];
  const float* W   = (const float*)d_in[1];
  const float* bWp = (const float*)d_in[2];
  const float* U   = (const float*)d_in[3];
  const float* bUp = (const float*)d_in[4];
  float* out   = (float*)d_out;
  float* hlast = out + (size_t)64 * 1024 * 1024;
  float* clast = hlast + 64 * 1024;

  char* base = (char*)d_ws;
  unsigned short* Wt  = (unsigned short*)base;  base += 8388608;   // [4096][1024] bf16
  unsigned short* Ut  = (unsigned short*)base;  base += 8388608;   // [4096][1024] bf16
  unsigned long long* hbs = (unsigned long long*)base; base += 524288;  // [2][4][64KB] tagged h
  float* cstate       = (float*)base;           base += 262144;    // [64][1024] f32
  size_t fixed = (size_t)(base - (char*)d_ws);
  size_t avail = ws_size > fixed ? ws_size - fixed : 0;
  int SC = 1024;
  while (SC > 8 && (size_t)SC * 655360ull > avail) SC >>= 1;
  unsigned short* Abuf = (unsigned short*)base; base += (size_t)SC * 131072;  // [SC*64][1024] bf16
  unsigned short* xpb  = (unsigned short*)base;                               // [SC*64][4096] bf16

  hipMemsetAsync(hbs, 0, 524288, stream);       // h0 = 0 with tag 0 (both parities)

  k_transpose_bf16<<<dim3(16, 16, 4), 256, 0, stream>>>(W, Wt);
  k_transpose_bf16<<<dim3(16, 16, 4), 256, 0, stream>>>(U, Ut);

  int nch = 1024 / SC;
  for (int cc = 0; cc < nch; cc++){
    int s0 = cc * SC;
    k_convert_x<<<SC * 64, 256, 0, stream>>>(input_emb, Abuf, s0);
    k_gemm_xproj<<<dim3(SC / 2, 32), 256, 0, stream>>>(Abuf, Wt, bWp, bUp, xpb);
    k_lstm_rec<<<128, 256, 0, stream>>>(xpb, Ut, hbs, cstate, out, hlast, clast, s0, SC);
  }
}

// Round 15
// 8998.172 us; speedup vs baseline: 1.4899x; 1.4899x over previous
//
#include <hip/hip_runtime.h>
#include <hip/hip_bf16.h>
#include <stdint.h>

// LSTM B=64 S=1024 D=1024 H=1024, gates f,i,o,g all sigmoid.
// Phase 1: xproj = x@W + bW + bU  (bf16 MFMA GEMM)
// Phase 2: persistent recurrent kernel, 128 WGs = 4 batch-groups x 32 col-WGs.
//   R15 = R12 minus the L3 transaction storm:
//   (1) consumer h loads = plain coalesced dwordx4 (was 128 uncoalesced 8B atomics
//       per subtile), coherence via one acquire fence per step after chunk-0 flags
//       (R10-proven fence+plain-consume pattern; compiler barrier after each wait).
//   (2) flag poll: lanes 0-7 only (8 transactions/iter, was 64 duplicated).
//   Producer publish / flags / barriers / glds: byte-identical to R12.

typedef __attribute__((ext_vector_type(8))) short short8;
typedef __attribute__((ext_vector_type(4))) float floatx4;
typedef __attribute__((ext_vector_type(2))) float floatx2;

__device__ __forceinline__ unsigned short f2bf(float x){
  union { float f; unsigned int u; } v; v.f = x;
  unsigned int r = v.u + 0x7fffu + ((v.u >> 16) & 1u);
  return (unsigned short)(r >> 16);
}
__device__ __forceinline__ float bf2f(unsigned short b){
  union { unsigned int u; float f; } v; v.u = ((unsigned int)b) << 16; return v.f;
}
__device__ __forceinline__ float fsigmoid(float x){ return 1.0f / (1.0f + __expf(-x)); }
__device__ __forceinline__ float ftanh(float x){ return 1.0f - 2.0f / (1.0f + __expf(2.0f * x)); }

// ---- transpose [g][d][h] fp32 -> [g][h][d] bf16 (per-gate 1024x1024) ----
__global__ void k_transpose_bf16(const float* __restrict__ src, unsigned short* __restrict__ dst){
  __shared__ float tile[64][65];
  const int g  = blockIdx.z;
  const int d0 = blockIdx.x * 64;
  const int h0 = blockIdx.y * 64;
  const int t  = threadIdx.x;
  const float* s    = src + ((size_t)g << 20);
  unsigned short* o = dst + ((size_t)g << 20);
  #pragma unroll
  for (int i = 0; i < 16; i++){
    int e = i * 256 + t;
    int r = e >> 6, c = e & 63;
    tile[r][c] = s[(size_t)(d0 + r) * 1024 + (h0 + c)];
  }
  __syncthreads();
  #pragma unroll
  for (int i = 0; i < 16; i++){
    int e = i * 256 + t;
    int a = e >> 6, bb = e & 63;
    o[(size_t)(h0 + a) * 1024 + (d0 + bb)] = f2bf(tile[bb][a]);
  }
}

// ---- convert input chunk (B,S,D) fp32 -> Abuf[(sl*64+b)][d] bf16 ----
__global__ void k_convert_x(const float* __restrict__ inp, unsigned short* __restrict__ abuf, int s0){
  int idx = blockIdx.x * 256 + threadIdx.x;
  int e = idx * 4;
  int r = e >> 10, d = e & 1023;
  int b = r & 63, sl = r >> 6;
  floatx4 v = *(const floatx4*)(inp + ((size_t)(b * 1024 + (s0 + sl)) * 1024 + d));
  unsigned long long pk = (unsigned long long)f2bf(v[0])
                        | ((unsigned long long)f2bf(v[1]) << 16)
                        | ((unsigned long long)f2bf(v[2]) << 32)
                        | ((unsigned long long)f2bf(v[3]) << 48);
  *(unsigned long long*)(abuf + (size_t)r * 1024 + d) = pk;
}

// ---- xproj GEMM: C[M][4096] = A[M][1024] @ Bt^T + (bW+bU), bf16 out ----
__global__ void __launch_bounds__(256) k_gemm_xproj(
    const unsigned short* __restrict__ A,
    const unsigned short* __restrict__ Bt,
    const float* __restrict__ bW,
    const float* __restrict__ bU,
    unsigned short* __restrict__ Cc)
{
  __shared__ unsigned short As[2][128][64];
  __shared__ unsigned short Bs[2][128][64];
  const int t = threadIdx.x;
  const int w = t >> 6;
  const int lane = t & 63;
  const int m0 = blockIdx.x * 128;
  const int n0 = blockIdx.y * 128;
  floatx4 acc[4][4];
  #pragma unroll
  for (int i = 0; i < 4; i++)
    #pragma unroll
    for (int j = 0; j < 4; j++)
      acc[i][j] = (floatx4){0.f, 0.f, 0.f, 0.f};

  auto stage = [&](int bufi, int kt){
    #pragma unroll
    for (int i = 0; i < 4; i++){
      int chunk = i * 256 + t;
      int r = chunk >> 3, j = chunk & 7;
      int js = j ^ (r & 7);
      __builtin_amdgcn_global_load_lds(
        (const __attribute__((address_space(1))) unsigned int*)(A + (size_t)(m0 + r) * 1024 + kt * 64 + js * 8),
        (__attribute__((address_space(3))) unsigned int*)(&As[bufi][0][0] + (i * 256 + w * 64) * 8), 16, 0, 0);
    }
    #pragma unroll
    for (int i = 0; i < 4; i++){
      int chunk = i * 256 + t;
      int r = chunk >> 3, j = chunk & 7;
      int js = j ^ (r & 7);
      __builtin_amdgcn_global_load_lds(
        (const __attribute__((address_space(1))) unsigned int*)(Bt + (size_t)(n0 + r) * 1024 + kt * 64 + js * 8),
        (__attribute__((address_space(3))) unsigned int*)(&Bs[bufi][0][0] + (i * 256 + w * 64) * 8), 16, 0, 0);
    }
  };

  auto compute = [&](int bufi){
    const int mi0 = (w >> 1) * 64;
    const int ni0 = (w & 1) * 64;
    #pragma unroll
    for (int kc = 0; kc < 2; kc++){
      short8 af[4], bfr[4];
      #pragma unroll
      for (int mi = 0; mi < 4; mi++){
        int row = mi0 + mi * 16 + (lane & 15);
        int j = kc * 4 + (lane >> 4);
        af[mi] = *(const short8*)&As[bufi][row][(j ^ (row & 7)) * 8];
      }
      #pragma unroll
      for (int ni = 0; ni < 4; ni++){
        int row = ni0 + ni * 16 + (lane & 15);
        int j = kc * 4 + (lane >> 4);
        bfr[ni] = *(const short8*)&Bs[bufi][row][(j ^ (row & 7)) * 8];
      }
      #pragma unroll
      for (int mi = 0; mi < 4; mi++)
        #pragma unroll
        for (int ni = 0; ni < 4; ni++)
          acc[mi][ni] = __builtin_amdgcn_mfma_f32_16x16x32_bf16(af[mi], bfr[ni], acc[mi][ni], 0, 0, 0);
    }
  };

  stage(0, 0);
  int buf = 0;
  for (int kt = 0; kt < 16; kt++){
    __syncthreads();
    if (kt < 15) stage(buf ^ 1, kt + 1);
    compute(buf);
    buf ^= 1;
  }

  {
    const int mi0 = (w >> 1) * 64;
    const int ni0 = (w & 1) * 64;
    #pragma unroll
    for (int ni = 0; ni < 4; ni++){
      int col = n0 + ni0 + ni * 16 + (lane & 15);
      float bias = bW[col] + bU[col];
      #pragma unroll
      for (int mi = 0; mi < 4; mi++){
        int mrow = m0 + mi0 + mi * 16 + (lane >> 4) * 4;
        #pragma unroll
        for (int r = 0; r < 4; r++)
          Cc[(size_t)(mrow + r) * 4096 + col] = f2bf(acc[mi][ni][r] + bias);
      }
    }
  }
}

// ---- persistent recurrent kernel: 128 WGs = 4 groups(16 batches) x 32 col-WGs ----
// Group buffer (per parity, per group): 32KB = 32 subtiles x 1KB. Subtile kc holds the
// MFMA A-frag for k in [kc*32,kc*32+32): element (r, k=kc*32+jj*8+e) at byte
// (jj*16 + r)*16 + e*2, r = batch row 0..15. Consumer lane l reads bytes [l*16,l*16+16)
// of each subtile via PLAIN coalesced dwordx4 loads (fresh after per-step acquire fence).
// Producer thread (b,cc2): one 4B AGENT-scope atomic store. flags[g*32+j] per WG.
__global__ void __launch_bounds__(256, 1) k_lstm_rec(
    const unsigned short* __restrict__ xp,   // [SC*64][4096] bf16
    const unsigned short* __restrict__ Ut,   // [4096][1024] bf16 (gate-major rows)
    unsigned short* hbs,                     // [2][4][32768B] h group buffers
    float* cstate,                           // [64][1024]
    float* __restrict__ out,                 // (B,S,H) fp32
    float* __restrict__ hlast,
    float* __restrict__ clast,
    int* flags,                              // [4][32] ints (group-contiguous lines)
    int s_base, int SC)
{
  const int t = threadIdx.x;
  const int w = t >> 6;            // wave = gate
  const int lane = t & 63;
  const int wgid = blockIdx.x;
  const int g  = wgid & 3;         // batch group: batches 16g..16g+15
  const int j  = wgid >> 2;        // col-slice: h-cols [j*32, j*32+32)
  const int B0 = g * 16;
  const int gc0 = j * 32;

  __shared__ float glds[4][16][33];          // gate exchange [gate][batch][col]

  // U in VGPRs: wave w = gate w, cols gc0..gc0+31 (two 16-col N-tiles), full K=1024.
  short8 bfrag0[32], bfrag1[32];
  {
    const unsigned short* bp0 = Ut + (size_t)(w * 1024 + gc0 + (lane & 15)) * 1024 + (lane >> 4) * 8;
    const unsigned short* bp1 = bp0 + (size_t)16 * 1024;
    #pragma unroll
    for (int kc = 0; kc < 32; kc++){
      bfrag0[kc] = *(const short8*)(bp0 + kc * 32);
      bfrag1[kc] = *(const short8*)(bp1 + kc * 32);
    }
  }

  const int b   = t >> 4;          // local batch 0..15 owned in epilogue
  const int cc2 = (t & 15) * 2;    // 2 local h-cols owned: cc2, cc2+1
  floatx2 cst;
  if (s_base == 0) cst = (floatx2){0.f, 0.f};
  else             cst = *(const floatx2*)&cstate[(size_t)(B0 + b) * 1024 + gc0 + cc2];

  int bail = 20000000;
  const int fb = g * 32;

  for (int sl = 0; sl < SC; sl++){
    const int s = s_base + sl;
    const int p = s & 1;

    const char* gsrc = (const char*)hbs + ((size_t)p * 4 + g) * 32768;
    floatx4 acc0 = (floatx4){0.f,0.f,0.f,0.f};
    floatx4 acc1 = (floatx4){0.f,0.f,0.f,0.f};

    // per-chunk wait: lanes 0-7 poll the 8 producer flags of chunk c (8 transactions)
    auto wait_chunk = [&](int c){
      if (s == 0) return;
      while (true){
        bool ok = true;
        if (lane < 8){
          int v = __hip_atomic_load(&flags[fb + c * 8 + lane], __ATOMIC_RELAXED, __HIP_MEMORY_SCOPE_AGENT);
          ok = (v >= s);
        }
        if (__all(ok)) break;
        __builtin_amdgcn_s_sleep(1);
        if (--bail < 0) break;
      }
      asm volatile("" ::: "memory");   // stop plain-load hoisting above the confirm
    };

    short8 hA[8], hB[8];
    auto issue8 = [&](short8 (&h)[8], int ch){
      #pragma unroll
      for (int i = 0; i < 8; i++)
        h[i] = *(const short8*)(gsrc + (ch * 8 + i) * 1024 + lane * 16);
    };
    auto crunch8 = [&](short8 (&h)[8], int ch){
      #pragma unroll
      for (int i = 0; i < 8; i++){
        acc0 = __builtin_amdgcn_mfma_f32_16x16x32_bf16(h[i], bfrag0[ch * 8 + i], acc0, 0, 0, 0);
        acc1 = __builtin_amdgcn_mfma_f32_16x16x32_bf16(h[i], bfrag1[ch * 8 + i], acc1, 0, 0, 0);
      }
    };

    wait_chunk(0);
    __builtin_amdgcn_fence(__ATOMIC_ACQUIRE, "agent");  // invalidate L1/L2 once per step

    // xp prefetch after the fence (fence drains vmcnt); latency hides under chunks
    unsigned int xu[4];
    {
      const unsigned short* xr = xp + ((size_t)(sl * 64 + B0 + b)) * 4096 + gc0 + cc2;
      #pragma unroll
      for (int gg = 0; gg < 4; gg++) xu[gg] = *(const unsigned int*)(xr + gg * 1024);
    }

    issue8(hA, 0);
    wait_chunk(1);
    issue8(hB, 1);
    crunch8(hA, 0);
    wait_chunk(2);
    issue8(hA, 2);
    crunch8(hB, 1);
    wait_chunk(3);
    issue8(hB, 3);
    crunch8(hA, 2);
    crunch8(hB, 3);

    // publish gate values (all 16 rows real). C: row=(l>>4)*4+reg, col=l&15.
    {
      const int r0 = (lane >> 4) * 4;
      const int cl = lane & 15;
      #pragma unroll
      for (int r = 0; r < 4; r++){
        glds[w][r0 + r][cl]      = acc0[r];
        glds[w][r0 + r][16 + cl] = acc1[r];
      }
    }
    __syncthreads();                                    // B3

    // epilogue: thread owns (b, cc2) and (b, cc2+1)
    float hout[2];
    #pragma unroll
    for (int d = 0; d < 2; d++){
      float fv = fsigmoid(glds[0][b][cc2 + d] + bf2f((unsigned short)(xu[0] >> (16 * d))));
      float iv = fsigmoid(glds[1][b][cc2 + d] + bf2f((unsigned short)(xu[1] >> (16 * d))));
      float ov = fsigmoid(glds[2][b][cc2 + d] + bf2f((unsigned short)(xu[2] >> (16 * d))));
      float gv = fsigmoid(glds[3][b][cc2 + d] + bf2f((unsigned short)(xu[3] >> (16 * d))));  // sigmoid, not tanh
      float cv = fv * cst[d] + iv * gv;
      cst[d] = cv;
      hout[d] = ov * ftanh(cv);
    }

    // publish h: per-thread 4B AGENT-scope atomic store (L3 coherence point).
    {
      unsigned int hv = (unsigned int)f2bf(hout[0]) | ((unsigned int)f2bf(hout[1]) << 16);
      unsigned int* dst = (unsigned int*)((char*)hbs + ((size_t)(p ^ 1) * 4 + g) * 32768 + j * 1024
                + (((cc2 >> 3) * 16 + b) << 4) + ((cc2 & 7) << 1));
      __hip_atomic_store(dst, hv, __ATOMIC_RELAXED, __HIP_MEMORY_SCOPE_AGENT);
    }

    if (s == 1023){
      *(floatx2*)&hlast[(size_t)(B0 + b) * 1024 + gc0 + cc2] = (floatx2){hout[0], hout[1]};
      *(floatx2*)&clast[(size_t)(B0 + b) * 1024 + gc0 + cc2] = cst;
    }

    asm volatile("s_waitcnt vmcnt(0)" ::: "memory");    // h stores acked
    __syncthreads();                                    // B4: whole WG published
    if (t == 0)
      __hip_atomic_store(&flags[fb + j], s + 1, __ATOMIC_RELAXED, __HIP_MEMORY_SCOPE_AGENT);

    // out store off the critical path
    *(floatx2*)&out[((size_t)(B0 + b) * 1024 + s) * 1024 + gc0 + cc2] = (floatx2){hout[0], hout[1]};
  }

  *(floatx2*)&cstate[(size_t)(B0 + b) * 1024 + gc0 + cc2] = cst;
}

extern "C" void kernel_launch(void* const* d_in, const int* in_sizes, int n_in,
                              void* d_out, int out_size, void* d_ws, size_t ws_size,
                              hipStream_t stream)
{
  (void)in_sizes; (void)n_in; (void)out_size;
  const float* input_emb = (const float*)d_in[0];
  const float* W   = (const float*)d_in[1];
  const float* bWp = (const float*)d_in[2];
  const float* U   = (const float*)d_in[3];
  const float* bUp = (const float*)d_in[4];
  float* out   = (float*)d_out;
  float* hlast = out + (size_t)64 * 1024 * 1024;
  float* clast = hlast + 64 * 1024;

  char* base = (char*)d_ws;
  unsigned short* Wt  = (unsigned short*)base;  base += 8388608;   // [4096][1024] bf16
  unsigned short* Ut  = (unsigned short*)base;  base += 8388608;   // [4096][1024] bf16
  unsigned short* hbs = (unsigned short*)base;  base += 262144;    // [2][4][32KB] group h
  float* cstate       = (float*)base;           base += 262144;    // [64][1024] f32
  int* flags          = (int*)base;             base += 8192;      // [4][32] ints (+pad)
  size_t fixed = (size_t)(base - (char*)d_ws);
  size_t avail = ws_size > fixed ? ws_size - fixed : 0;
  int SC = 1024;
  while (SC > 8 && (size_t)SC * 655360ull > avail) SC >>= 1;
  unsigned short* Abuf = (unsigned short*)base; base += (size_t)SC * 131072;  // [SC*64][1024] bf16
  unsigned short* xpb  = (unsigned short*)base;                               // [SC*64][4096] bf16

  hipMemsetAsync(flags, 0, 8192, stream);
  hipMemsetAsync(hbs, 0, 262144, stream);       // h0 = 0 (both parities)

  k_transpose_bf16<<<dim3(16, 16, 4), 256, 0, stream>>>(W, Wt);
  k_transpose_bf16<<<dim3(16, 16, 4), 256, 0, stream>>>(U, Ut);

  int nch = 1024 / SC;
  for (int cc = 0; cc < nch; cc++){
    int s0 = cc * SC;
    k_convert_x<<<SC * 64, 256, 0, stream>>>(input_emb, Abuf, s0);
    k_gemm_xproj<<<dim3(SC / 2, 32), 256, 0, stream>>>(Abuf, Wt, bWp, bUp, xpb);
    k_lstm_rec<<<128, 256, 0, stream>>>(xpb, Ut, hbs, cstate, out, hlast, clast, flags, s0, SC);
  }
}

// Round 16
// 6998.881 us; speedup vs baseline: 1.9154x; 1.2857x over previous
//
#include <hip/hip_runtime.h>
#include <hip/hip_bf16.h>
#include <stdint.h>

// LSTM B=64 S=1024 D=1024 H=1024, gates f,i,o,g all sigmoid.
// Phase 1: xproj = x@W + bW + bU  (bf16 MFMA GEMM)
// Phase 2: persistent recurrent kernel, 256 WGs = 4 batch-groups x 64 col-WGs.
//   R16 = R12 dataflow with 16 cols/WG so the U slice (bfrag[32] = 128 VGPRs) is
//   GENUINELY register-resident (R4-proven shape; R10-R15's 256-VGPR slice was
//   silently rematerialized -> 64KB/wave/step L2 re-stream, the dominant step cost).
//   Consume: agent-scope atomic loads (no fence). Publish: 4B agent atomic stores.
//   Subtile kc is fed by producers 2kc,2kc+1 -> 16 flags per 8-subtile chunk.

typedef __attribute__((ext_vector_type(8))) short short8;
typedef __attribute__((ext_vector_type(4))) float floatx4;

__device__ __forceinline__ unsigned short f2bf(float x){
  union { float f; unsigned int u; } v; v.f = x;
  unsigned int r = v.u + 0x7fffu + ((v.u >> 16) & 1u);
  return (unsigned short)(r >> 16);
}
__device__ __forceinline__ float bf2f(unsigned short b){
  union { unsigned int u; float f; } v; v.u = ((unsigned int)b) << 16; return v.f;
}
__device__ __forceinline__ float fsigmoid(float x){ return 1.0f / (1.0f + __expf(-x)); }
__device__ __forceinline__ float ftanh(float x){ return 1.0f - 2.0f / (1.0f + __expf(2.0f * x)); }

// ---- transpose [g][d][h] fp32 -> [g][h][d] bf16 (per-gate 1024x1024) ----
__global__ void k_transpose_bf16(const float* __restrict__ src, unsigned short* __restrict__ dst){
  __shared__ float tile[64][65];
  const int g  = blockIdx.z;
  const int d0 = blockIdx.x * 64;
  const int h0 = blockIdx.y * 64;
  const int t  = threadIdx.x;
  const float* s    = src + ((size_t)g << 20);
  unsigned short* o = dst + ((size_t)g << 20);
  #pragma unroll
  for (int i = 0; i < 16; i++){
    int e = i * 256 + t;
    int r = e >> 6, c = e & 63;
    tile[r][c] = s[(size_t)(d0 + r) * 1024 + (h0 + c)];
  }
  __syncthreads();
  #pragma unroll
  for (int i = 0; i < 16; i++){
    int e = i * 256 + t;
    int a = e >> 6, bb = e & 63;
    o[(size_t)(h0 + a) * 1024 + (d0 + bb)] = f2bf(tile[bb][a]);
  }
}

// ---- convert input chunk (B,S,D) fp32 -> Abuf[(sl*64+b)][d] bf16 ----
__global__ void k_convert_x(const float* __restrict__ inp, unsigned short* __restrict__ abuf, int s0){
  int idx = blockIdx.x * 256 + threadIdx.x;
  int e = idx * 4;
  int r = e >> 10, d = e & 1023;
  int b = r & 63, sl = r >> 6;
  floatx4 v = *(const floatx4*)(inp + ((size_t)(b * 1024 + (s0 + sl)) * 1024 + d));
  unsigned long long pk = (unsigned long long)f2bf(v[0])
                        | ((unsigned long long)f2bf(v[1]) << 16)
                        | ((unsigned long long)f2bf(v[2]) << 32)
                        | ((unsigned long long)f2bf(v[3]) << 48);
  *(unsigned long long*)(abuf + (size_t)r * 1024 + d) = pk;
}

// ---- xproj GEMM: C[M][4096] = A[M][1024] @ Bt^T + (bW+bU), bf16 out ----
__global__ void __launch_bounds__(256) k_gemm_xproj(
    const unsigned short* __restrict__ A,
    const unsigned short* __restrict__ Bt,
    const float* __restrict__ bW,
    const float* __restrict__ bU,
    unsigned short* __restrict__ Cc)
{
  __shared__ unsigned short As[2][128][64];
  __shared__ unsigned short Bs[2][128][64];
  const int t = threadIdx.x;
  const int w = t >> 6;
  const int lane = t & 63;
  const int m0 = blockIdx.x * 128;
  const int n0 = blockIdx.y * 128;
  floatx4 acc[4][4];
  #pragma unroll
  for (int i = 0; i < 4; i++)
    #pragma unroll
    for (int j = 0; j < 4; j++)
      acc[i][j] = (floatx4){0.f, 0.f, 0.f, 0.f};

  auto stage = [&](int bufi, int kt){
    #pragma unroll
    for (int i = 0; i < 4; i++){
      int chunk = i * 256 + t;
      int r = chunk >> 3, j = chunk & 7;
      int js = j ^ (r & 7);
      __builtin_amdgcn_global_load_lds(
        (const __attribute__((address_space(1))) unsigned int*)(A + (size_t)(m0 + r) * 1024 + kt * 64 + js * 8),
        (__attribute__((address_space(3))) unsigned int*)(&As[bufi][0][0] + (i * 256 + w * 64) * 8), 16, 0, 0);
    }
    #pragma unroll
    for (int i = 0; i < 4; i++){
      int chunk = i * 256 + t;
      int r = chunk >> 3, j = chunk & 7;
      int js = j ^ (r & 7);
      __builtin_amdgcn_global_load_lds(
        (const __attribute__((address_space(1))) unsigned int*)(Bt + (size_t)(n0 + r) * 1024 + kt * 64 + js * 8),
        (__attribute__((address_space(3))) unsigned int*)(&Bs[bufi][0][0] + (i * 256 + w * 64) * 8), 16, 0, 0);
    }
  };

  auto compute = [&](int bufi){
    const int mi0 = (w >> 1) * 64;
    const int ni0 = (w & 1) * 64;
    #pragma unroll
    for (int kc = 0; kc < 2; kc++){
      short8 af[4], bfr[4];
      #pragma unroll
      for (int mi = 0; mi < 4; mi++){
        int row = mi0 + mi * 16 + (lane & 15);
        int j = kc * 4 + (lane >> 4);
        af[mi] = *(const short8*)&As[bufi][row][(j ^ (row & 7)) * 8];
      }
      #pragma unroll
      for (int ni = 0; ni < 4; ni++){
        int row = ni0 + ni * 16 + (lane & 15);
        int j = kc * 4 + (lane >> 4);
        bfr[ni] = *(const short8*)&Bs[bufi][row][(j ^ (row & 7)) * 8];
      }
      #pragma unroll
      for (int mi = 0; mi < 4; mi++)
        #pragma unroll
        for (int ni = 0; ni < 4; ni++)
          acc[mi][ni] = __builtin_amdgcn_mfma_f32_16x16x32_bf16(af[mi], bfr[ni], acc[mi][ni], 0, 0, 0);
    }
  };

  stage(0, 0);
  int buf = 0;
  for (int kt = 0; kt < 16; kt++){
    __syncthreads();
    if (kt < 15) stage(buf ^ 1, kt + 1);
    compute(buf);
    buf ^= 1;
  }

  {
    const int mi0 = (w >> 1) * 64;
    const int ni0 = (w & 1) * 64;
    #pragma unroll
    for (int ni = 0; ni < 4; ni++){
      int col = n0 + ni0 + ni * 16 + (lane & 15);
      float bias = bW[col] + bU[col];
      #pragma unroll
      for (int mi = 0; mi < 4; mi++){
        int mrow = m0 + mi0 + mi * 16 + (lane >> 4) * 4;
        #pragma unroll
        for (int r = 0; r < 4; r++)
          Cc[(size_t)(mrow + r) * 4096 + col] = f2bf(acc[mi][ni][r] + bias);
      }
    }
  }
}

// ---- persistent recurrent kernel: 256 WGs = 4 groups(16 batches) x 64 col-WGs ----
// Group buffer (per parity, per group): 32KB = 32 subtiles x 1KB. Subtile kc holds the
// MFMA A-frag for k in [kc*32,kc*32+32): element (r, k=kc*32+jj*8+e) at byte
// (jj*16 + r)*16 + e*2, r = batch row 0..15. Consumer lane l reads bytes [l*16,l*16+16)
// of each subtile via 8B AGENT-scope atomic loads (L3-coherent, L2 untouched).
// Producer WG j owns cols [j*16, j*16+16) = half of subtile j>>1 (k_local = (j&1)*16+cc).
// Even lanes publish 4B packed pairs. flags[g*64+j] per WG; chunk c needs 16 producers.
__global__ void __launch_bounds__(256, 1) k_lstm_rec(
    const unsigned short* __restrict__ xp,   // [SC*64][4096] bf16
    const unsigned short* __restrict__ Ut,   // [4096][1024] bf16 (gate-major rows)
    unsigned short* hbs,                     // [2][4][32768B] h group buffers
    float* cstate,                           // [64][1024]
    float* __restrict__ out,                 // (B,S,H) fp32
    float* __restrict__ hlast,
    float* __restrict__ clast,
    int* flags,                              // [4][64] ints
    int s_base, int SC)
{
  const int t = threadIdx.x;
  const int w = t >> 6;            // wave = gate
  const int lane = t & 63;
  const int wgid = blockIdx.x;
  const int g  = wgid & 3;         // batch group: batches 16g..16g+15
  const int j  = wgid >> 2;        // col-slice 0..63: h-cols [j*16, j*16+16)
  const int B0 = g * 16;
  const int gc0 = j * 16;

  __shared__ float glds[4][16][17];          // gate exchange [gate][batch][col]

  // U in VGPRs: wave w = gate w, cols gc0..gc0+15 (ONE 16-col N-tile), full K=1024.
  // 32 frags = 128 VGPRs - the R4-proven register-resident shape.
  short8 bfrag[32];
  {
    const unsigned short* bp = Ut + (size_t)(w * 1024 + gc0 + (lane & 15)) * 1024 + (lane >> 4) * 8;
    #pragma unroll
    for (int kc = 0; kc < 32; kc++)
      bfrag[kc] = *(const short8*)(bp + kc * 32);
  }

  const int b  = t >> 4;           // local batch 0..15 owned in epilogue
  const int cc = t & 15;           // 1 local h-col owned
  float cst;
  if (s_base == 0) cst = 0.f;
  else             cst = cstate[(size_t)(B0 + b) * 1024 + gc0 + cc];

  int bail = 20000000;
  const int fb = g * 64;

  for (int sl = 0; sl < SC; sl++){
    const int s = s_base + sl;
    const int p = s & 1;

    // xp prefetch (independent of h) BEFORE the waits: 1 col per gate (2B each)
    unsigned short xv[4];
    {
      const unsigned short* xr = xp + ((size_t)(sl * 64 + B0 + b)) * 4096 + gc0 + cc;
      #pragma unroll
      for (int gg = 0; gg < 4; gg++) xv[gg] = xr[gg * 1024];
    }
    __builtin_amdgcn_sched_barrier(0);

    const char* gsrc = (const char*)hbs + ((size_t)p * 4 + g) * 32768;
    floatx4 acc = (floatx4){0.f,0.f,0.f,0.f};

    // per-chunk wait: lanes 0-15 poll the 16 producer flags of chunk c
    auto wait_chunk = [&](int c){
      if (s == 0) return;
      while (true){
        bool ok = true;
        if (lane < 16){
          int v = __hip_atomic_load(&flags[fb + c * 16 + lane], __ATOMIC_RELAXED, __HIP_MEMORY_SCOPE_AGENT);
          ok = (v >= s);
        }
        if (__all(ok)) break;
        __builtin_amdgcn_s_sleep(1);
        if (--bail < 0) break;
      }
      asm volatile("" ::: "memory");
    };

    unsigned long long loA[8], hiA[8], loB[8], hiB[8];
    auto issue8 = [&](unsigned long long (&lo)[8], unsigned long long (&hi)[8], int ch){
      #pragma unroll
      for (int i = 0; i < 8; i++){
        const unsigned long long* sp2 = (const unsigned long long*)(gsrc + (ch * 8 + i) * 1024 + lane * 16);
        lo[i] = __hip_atomic_load(sp2,     __ATOMIC_RELAXED, __HIP_MEMORY_SCOPE_AGENT);
        hi[i] = __hip_atomic_load(sp2 + 1, __ATOMIC_RELAXED, __HIP_MEMORY_SCOPE_AGENT);
      }
    };
    auto crunch8 = [&](unsigned long long (&lo)[8], unsigned long long (&hi)[8], int ch){
      #pragma unroll
      for (int i = 0; i < 8; i++){
        union { unsigned long long q[2]; short8 v; } u;
        u.q[0] = lo[i]; u.q[1] = hi[i];
        acc = __builtin_amdgcn_mfma_f32_16x16x32_bf16(u.v, bfrag[ch * 8 + i], acc, 0, 0, 0);
      }
    };

    wait_chunk(0);
    issue8(loA, hiA, 0);
    wait_chunk(1);
    issue8(loB, hiB, 1);
    crunch8(loA, hiA, 0);
    wait_chunk(2);
    issue8(loA, hiA, 2);
    crunch8(loB, hiB, 1);
    wait_chunk(3);
    issue8(loB, hiB, 3);
    crunch8(loA, hiA, 2);
    crunch8(loB, hiB, 3);

    // publish gate values (16 rows x 16 cols). C: row=(l>>4)*4+reg, col=l&15.
    {
      const int r0 = (lane >> 4) * 4;
      const int cl = lane & 15;
      #pragma unroll
      for (int r = 0; r < 4; r++)
        glds[w][r0 + r][cl] = acc[r];
    }
    __syncthreads();                                    // B3

    // epilogue: thread owns (b, cc) - all 256 threads active
    float fv = fsigmoid(glds[0][b][cc] + bf2f(xv[0]));
    float iv = fsigmoid(glds[1][b][cc] + bf2f(xv[1]));
    float ov = fsigmoid(glds[2][b][cc] + bf2f(xv[2]));
    float gv = fsigmoid(glds[3][b][cc] + bf2f(xv[3]));   // reference: sigmoid, not tanh
    cst = fv * cst + iv * gv;
    float hout = ov * ftanh(cst);

    // publish h: pack col pair via shfl, even lanes store 4B agent-scope atomic.
    // k_local = (j&1)*16 + cc; dst subtile = j>>1.
    {
      unsigned int my = (unsigned int)f2bf(hout);
      unsigned int nb = __shfl_down(my, 1);
      if (!(lane & 1)){
        const int kl = ((j & 1) << 4) + cc;             // even
        unsigned int* dst = (unsigned int*)((char*)hbs + ((size_t)(p ^ 1) * 4 + g) * 32768
                  + (size_t)(j >> 1) * 1024 + (((kl >> 3) * 16 + b) << 4) + ((kl & 7) << 1));
        __hip_atomic_store(dst, my | (nb << 16), __ATOMIC_RELAXED, __HIP_MEMORY_SCOPE_AGENT);
      }
    }

    if (s == 1023){
      hlast[(size_t)(B0 + b) * 1024 + gc0 + cc] = hout;
      clast[(size_t)(B0 + b) * 1024 + gc0 + cc] = cst;
    }

    asm volatile("s_waitcnt vmcnt(0)" ::: "memory");    // h stores acked at L3
    __syncthreads();                                    // B4: whole WG published
    if (t == 0)
      __hip_atomic_store(&flags[fb + j], s + 1, __ATOMIC_RELAXED, __HIP_MEMORY_SCOPE_AGENT);

    // out store off the critical path
    out[((size_t)(B0 + b) * 1024 + s) * 1024 + gc0 + cc] = hout;
  }

  cstate[(size_t)(B0 + b) * 1024 + gc0 + cc] = cst;
}

extern "C" void kernel_launch(void* const* d_in, const int* in_sizes, int n_in,
                              void* d_out, int out_size, void* d_ws, size_t ws_size,
                              hipStream_t stream)
{
  (void)in_sizes; (void)n_in; (void)out_size;
  const float* input_emb = (const float*)d_in[0];
  const float* W   = (const float*)d_in[1];
  const float* bWp = (const float*)d_in[2];
  const float* U   = (const float*)d_in[3];
  const float* bUp = (const float*)d_in[4];
  float* out   = (float*)d_out;
  float* hlast = out + (size_t)64 * 1024 * 1024;
  float* clast = hlast + 64 * 1024;

  char* base = (char*)d_ws;
  unsigned short* Wt  = (unsigned short*)base;  base += 8388608;   // [4096][1024] bf16
  unsigned short* Ut  = (unsigned short*)base;  base += 8388608;   // [4096][1024] bf16
  unsigned short* hbs = (unsigned short*)base;  base += 262144;    // [2][4][32KB] group h
  float* cstate       = (float*)base;           base += 262144;    // [64][1024] f32
  int* flags          = (int*)base;             base += 8192;      // [4][64] ints (+pad)
  size_t fixed = (size_t)(base - (char*)d_ws);
  size_t avail = ws_size > fixed ? ws_size - fixed : 0;
  int SC = 1024;
  while (SC > 8 && (size_t)SC * 655360ull > avail) SC >>= 1;
  unsigned short* Abuf = (unsigned short*)base; base += (size_t)SC * 131072;  // [SC*64][1024] bf16
  unsigned short* xpb  = (unsigned short*)base;                               // [SC*64][4096] bf16

  hipMemsetAsync(flags, 0, 8192, stream);
  hipMemsetAsync(hbs, 0, 262144, stream);       // h0 = 0 (both parities)

  k_transpose_bf16<<<dim3(16, 16, 4), 256, 0, stream>>>(W, Wt);
  k_transpose_bf16<<<dim3(16, 16, 4), 256, 0, stream>>>(U, Ut);

  int nch = 1024 / SC;
  for (int cc = 0; cc < nch; cc++){
    int s0 = cc * SC;
    k_convert_x<<<SC * 64, 256, 0, stream>>>(input_emb, Abuf, s0);
    k_gemm_xproj<<<dim3(SC / 2, 32), 256, 0, stream>>>(Abuf, Wt, bWp, bUp, xpb);
    k_lstm_rec<<<256, 256, 0, stream>>>(xpb, Ut, hbs, cstate, out, hlast, clast, flags, s0, SC);
  }
}

// Round 17
// 6994.190 us; speedup vs baseline: 1.9167x; 1.0007x over previous
//
#include <hip/hip_runtime.h>
#include <hip/hip_bf16.h>
#include <stdint.h>

// LSTM B=64 S=1024 D=1024 H=1024, gates f,i,o,g all sigmoid.
// Phase 1: xproj = x@W + bW + bU  (bf16 MFMA GEMM)
// Phase 2: persistent recurrent kernel, 128 WGs = 4 batch-groups x 32 col-WGs.
//   R17 = R12 + cooperative wave staging: wave w waits chunk-w flags, atomic-loads
//   its 8 subtiles (L3-coherent path), ds_writes them into the conflict-free LDS
//   subtile layout; one barrier; all waves crunch all 32 subtiles from LDS.
//   Cuts per-step global h transactions 4x (the R14/R15/R16-evidenced limiter).
//   Publish / flags / glds exchange / epilogue: byte-identical to R12.

typedef __attribute__((ext_vector_type(8))) short short8;
typedef __attribute__((ext_vector_type(4))) float floatx4;
typedef __attribute__((ext_vector_type(2))) float floatx2;

__device__ __forceinline__ unsigned short f2bf(float x){
  union { float f; unsigned int u; } v; v.f = x;
  unsigned int r = v.u + 0x7fffu + ((v.u >> 16) & 1u);
  return (unsigned short)(r >> 16);
}
__device__ __forceinline__ float bf2f(unsigned short b){
  union { unsigned int u; float f; } v; v.u = ((unsigned int)b) << 16; return v.f;
}
__device__ __forceinline__ float fsigmoid(float x){ return 1.0f / (1.0f + __expf(-x)); }
__device__ __forceinline__ float ftanh(float x){ return 1.0f - 2.0f / (1.0f + __expf(2.0f * x)); }

// ---- transpose [g][d][h] fp32 -> [g][h][d] bf16 (per-gate 1024x1024) ----
__global__ void k_transpose_bf16(const float* __restrict__ src, unsigned short* __restrict__ dst){
  __shared__ float tile[64][65];
  const int g  = blockIdx.z;
  const int d0 = blockIdx.x * 64;
  const int h0 = blockIdx.y * 64;
  const int t  = threadIdx.x;
  const float* s    = src + ((size_t)g << 20);
  unsigned short* o = dst + ((size_t)g << 20);
  #pragma unroll
  for (int i = 0; i < 16; i++){
    int e = i * 256 + t;
    int r = e >> 6, c = e & 63;
    tile[r][c] = s[(size_t)(d0 + r) * 1024 + (h0 + c)];
  }
  __syncthreads();
  #pragma unroll
  for (int i = 0; i < 16; i++){
    int e = i * 256 + t;
    int a = e >> 6, bb = e & 63;
    o[(size_t)(h0 + a) * 1024 + (d0 + bb)] = f2bf(tile[bb][a]);
  }
}

// ---- convert input chunk (B,S,D) fp32 -> Abuf[(sl*64+b)][d] bf16 ----
__global__ void k_convert_x(const float* __restrict__ inp, unsigned short* __restrict__ abuf, int s0){
  int idx = blockIdx.x * 256 + threadIdx.x;
  int e = idx * 4;
  int r = e >> 10, d = e & 1023;
  int b = r & 63, sl = r >> 6;
  floatx4 v = *(const floatx4*)(inp + ((size_t)(b * 1024 + (s0 + sl)) * 1024 + d));
  unsigned long long pk = (unsigned long long)f2bf(v[0])
                        | ((unsigned long long)f2bf(v[1]) << 16)
                        | ((unsigned long long)f2bf(v[2]) << 32)
                        | ((unsigned long long)f2bf(v[3]) << 48);
  *(unsigned long long*)(abuf + (size_t)r * 1024 + d) = pk;
}

// ---- xproj GEMM: C[M][4096] = A[M][1024] @ Bt^T + (bW+bU), bf16 out ----
__global__ void __launch_bounds__(256) k_gemm_xproj(
    const unsigned short* __restrict__ A,
    const unsigned short* __restrict__ Bt,
    const float* __restrict__ bW,
    const float* __restrict__ bU,
    unsigned short* __restrict__ Cc)
{
  __shared__ unsigned short As[2][128][64];
  __shared__ unsigned short Bs[2][128][64];
  const int t = threadIdx.x;
  const int w = t >> 6;
  const int lane = t & 63;
  const int m0 = blockIdx.x * 128;
  const int n0 = blockIdx.y * 128;
  floatx4 acc[4][4];
  #pragma unroll
  for (int i = 0; i < 4; i++)
    #pragma unroll
    for (int j = 0; j < 4; j++)
      acc[i][j] = (floatx4){0.f, 0.f, 0.f, 0.f};

  auto stage = [&](int bufi, int kt){
    #pragma unroll
    for (int i = 0; i < 4; i++){
      int chunk = i * 256 + t;
      int r = chunk >> 3, j = chunk & 7;
      int js = j ^ (r & 7);
      __builtin_amdgcn_global_load_lds(
        (const __attribute__((address_space(1))) unsigned int*)(A + (size_t)(m0 + r) * 1024 + kt * 64 + js * 8),
        (__attribute__((address_space(3))) unsigned int*)(&As[bufi][0][0] + (i * 256 + w * 64) * 8), 16, 0, 0);
    }
    #pragma unroll
    for (int i = 0; i < 4; i++){
      int chunk = i * 256 + t;
      int r = chunk >> 3, j = chunk & 7;
      int js = j ^ (r & 7);
      __builtin_amdgcn_global_load_lds(
        (const __attribute__((address_space(1))) unsigned int*)(Bt + (size_t)(n0 + r) * 1024 + kt * 64 + js * 8),
        (__attribute__((address_space(3))) unsigned int*)(&Bs[bufi][0][0] + (i * 256 + w * 64) * 8), 16, 0, 0);
    }
  };

  auto compute = [&](int bufi){
    const int mi0 = (w >> 1) * 64;
    const int ni0 = (w & 1) * 64;
    #pragma unroll
    for (int kc = 0; kc < 2; kc++){
      short8 af[4], bfr[4];
      #pragma unroll
      for (int mi = 0; mi < 4; mi++){
        int row = mi0 + mi * 16 + (lane & 15);
        int j = kc * 4 + (lane >> 4);
        af[mi] = *(const short8*)&As[bufi][row][(j ^ (row & 7)) * 8];
      }
      #pragma unroll
      for (int ni = 0; ni < 4; ni++){
        int row = ni0 + ni * 16 + (lane & 15);
        int j = kc * 4 + (lane >> 4);
        bfr[ni] = *(const short8*)&Bs[bufi][row][(j ^ (row & 7)) * 8];
      }
      #pragma unroll
      for (int mi = 0; mi < 4; mi++)
        #pragma unroll
        for (int ni = 0; ni < 4; ni++)
          acc[mi][ni] = __builtin_amdgcn_mfma_f32_16x16x32_bf16(af[mi], bfr[ni], acc[mi][ni], 0, 0, 0);
    }
  };

  stage(0, 0);
  int buf = 0;
  for (int kt = 0; kt < 16; kt++){
    __syncthreads();
    if (kt < 15) stage(buf ^ 1, kt + 1);
    compute(buf);
    buf ^= 1;
  }

  {
    const int mi0 = (w >> 1) * 64;
    const int ni0 = (w & 1) * 64;
    #pragma unroll
    for (int ni = 0; ni < 4; ni++){
      int col = n0 + ni0 + ni * 16 + (lane & 15);
      float bias = bW[col] + bU[col];
      #pragma unroll
      for (int mi = 0; mi < 4; mi++){
        int mrow = m0 + mi0 + mi * 16 + (lane >> 4) * 4;
        #pragma unroll
        for (int r = 0; r < 4; r++)
          Cc[(size_t)(mrow + r) * 4096 + col] = f2bf(acc[mi][ni][r] + bias);
      }
    }
  }
}

// ---- persistent recurrent kernel: 128 WGs = 4 groups(16 batches) x 32 col-WGs ----
// Group buffer (per parity, per group): 32KB = 32 subtiles x 1KB. Subtile kc holds the
// MFMA A-frag for k in [kc*32,kc*32+32): element (r, k=kc*32+jj*8+e) at byte
// (jj*16 + r)*16 + e*2, r = batch row 0..15.
// Staging: wave w waits chunk-w's 8 flags, atomic-loads subtiles [w*8,w*8+8) (lane l
// takes bytes [l*16,l*16+16) of each), ds_writes into hsh at the same offsets; one
// barrier; every wave crunches all 32 subtiles from LDS (ds_read_b128, conflict-free).
// Producer thread (b,cc2): one 4B AGENT-scope atomic store. flags[g*32+j] per WG.
__global__ void __launch_bounds__(256, 1) k_lstm_rec(
    const unsigned short* __restrict__ xp,   // [SC*64][4096] bf16
    const unsigned short* __restrict__ Ut,   // [4096][1024] bf16 (gate-major rows)
    unsigned short* hbs,                     // [2][4][32768B] h group buffers
    float* cstate,                           // [64][1024]
    float* __restrict__ out,                 // (B,S,H) fp32
    float* __restrict__ hlast,
    float* __restrict__ clast,
    int* flags,                              // [4][32] ints (group-contiguous lines)
    int s_base, int SC)
{
  const int t = threadIdx.x;
  const int w = t >> 6;            // wave = gate
  const int lane = t & 63;
  const int wgid = blockIdx.x;
  const int g  = wgid & 3;         // batch group: batches 16g..16g+15
  const int j  = wgid >> 2;        // col-slice: h-cols [j*32, j*32+32)
  const int B0 = g * 16;
  const int gc0 = j * 32;

  __shared__ char hsh[32 * 1024];            // staged group-h (A-frag subtiles)
  __shared__ float glds[4][16][33];          // gate exchange [gate][batch][col]

  // U slice per wave: cols gc0..gc0+31 (two 16-col N-tiles), full K=1024.
  short8 bfrag0[32], bfrag1[32];
  {
    const unsigned short* bp0 = Ut + (size_t)(w * 1024 + gc0 + (lane & 15)) * 1024 + (lane >> 4) * 8;
    const unsigned short* bp1 = bp0 + (size_t)16 * 1024;
    #pragma unroll
    for (int kc = 0; kc < 32; kc++){
      bfrag0[kc] = *(const short8*)(bp0 + kc * 32);
      bfrag1[kc] = *(const short8*)(bp1 + kc * 32);
    }
  }

  const int b   = t >> 4;          // local batch 0..15 owned in epilogue
  const int cc2 = (t & 15) * 2;    // 2 local h-cols owned: cc2, cc2+1
  floatx2 cst;
  if (s_base == 0) cst = (floatx2){0.f, 0.f};
  else             cst = *(const floatx2*)&cstate[(size_t)(B0 + b) * 1024 + gc0 + cc2];

  int bail = 20000000;
  const int fb = g * 32;

  for (int sl = 0; sl < SC; sl++){
    const int s = s_base + sl;
    const int p = s & 1;

    // xp prefetch (independent of h) before the wait: 2 cols per gate as one 4B load
    unsigned int xu[4];
    {
      const unsigned short* xr = xp + ((size_t)(sl * 64 + B0 + b)) * 4096 + gc0 + cc2;
      #pragma unroll
      for (int gg = 0; gg < 4; gg++) xu[gg] = *(const unsigned int*)(xr + gg * 1024);
    }
    __builtin_amdgcn_sched_barrier(0);

    const char* gsrc = (const char*)hbs + ((size_t)p * 4 + g) * 32768;

    // wave w: wait for chunk-w producers (8 flags, lanes 0-7 poll)
    if (s > 0){
      while (true){
        bool ok = true;
        if (lane < 8){
          int v = __hip_atomic_load(&flags[fb + w * 8 + lane], __ATOMIC_RELAXED, __HIP_MEMORY_SCOPE_AGENT);
          ok = (v >= s);
        }
        if (__all(ok)) break;
        __builtin_amdgcn_s_sleep(1);
        if (--bail < 0) break;
      }
      asm volatile("" ::: "memory");
    }

    // stage chunk w: atomic-load 8 subtiles (L3-coherent), ds_write into hsh
    #pragma unroll
    for (int i = 0; i < 8; i++){
      const int st = w * 8 + i;
      const unsigned long long* sp2 = (const unsigned long long*)(gsrc + st * 1024 + lane * 16);
      unsigned long long lo = __hip_atomic_load(sp2,     __ATOMIC_RELAXED, __HIP_MEMORY_SCOPE_AGENT);
      unsigned long long hi = __hip_atomic_load(sp2 + 1, __ATOMIC_RELAXED, __HIP_MEMORY_SCOPE_AGENT);
      union { unsigned long long q[2]; short8 v; } u;
      u.q[0] = lo; u.q[1] = hi;
      *(short8*)(hsh + st * 1024 + lane * 16) = u.v;
    }
    __syncthreads();                                    // B-stage: all 32 subtiles in LDS

    // crunch all 32 subtiles from LDS
    floatx4 acc0 = (floatx4){0.f,0.f,0.f,0.f};
    floatx4 acc1 = (floatx4){0.f,0.f,0.f,0.f};
    const char* hp = hsh + lane * 16;
    #pragma unroll
    for (int kc = 0; kc < 32; kc++){
      short8 af = *(const short8*)(hp + kc * 1024);
      acc0 = __builtin_amdgcn_mfma_f32_16x16x32_bf16(af, bfrag0[kc], acc0, 0, 0, 0);
      acc1 = __builtin_amdgcn_mfma_f32_16x16x32_bf16(af, bfrag1[kc], acc1, 0, 0, 0);
    }

    // publish gate values (all 16 rows real). C: row=(l>>4)*4+reg, col=l&15.
    {
      const int r0 = (lane >> 4) * 4;
      const int cl = lane & 15;
      #pragma unroll
      for (int r = 0; r < 4; r++){
        glds[w][r0 + r][cl]      = acc0[r];
        glds[w][r0 + r][16 + cl] = acc1[r];
      }
    }
    __syncthreads();                                    // B3

    // epilogue: thread owns (b, cc2) and (b, cc2+1)
    float hout[2];
    #pragma unroll
    for (int d = 0; d < 2; d++){
      float fv = fsigmoid(glds[0][b][cc2 + d] + bf2f((unsigned short)(xu[0] >> (16 * d))));
      float iv = fsigmoid(glds[1][b][cc2 + d] + bf2f((unsigned short)(xu[1] >> (16 * d))));
      float ov = fsigmoid(glds[2][b][cc2 + d] + bf2f((unsigned short)(xu[2] >> (16 * d))));
      float gv = fsigmoid(glds[3][b][cc2 + d] + bf2f((unsigned short)(xu[3] >> (16 * d))));  // sigmoid, not tanh
      float cv = fv * cst[d] + iv * gv;
      cst[d] = cv;
      hout[d] = ov * ftanh(cv);
    }

    // publish h: per-thread 4B AGENT-scope atomic store (L3 coherence point).
    {
      unsigned int hv = (unsigned int)f2bf(hout[0]) | ((unsigned int)f2bf(hout[1]) << 16);
      unsigned int* dst = (unsigned int*)((char*)hbs + ((size_t)(p ^ 1) * 4 + g) * 32768 + j * 1024
                + (((cc2 >> 3) * 16 + b) << 4) + ((cc2 & 7) << 1));
      __hip_atomic_store(dst, hv, __ATOMIC_RELAXED, __HIP_MEMORY_SCOPE_AGENT);
    }

    if (s == 1023){
      *(floatx2*)&hlast[(size_t)(B0 + b) * 1024 + gc0 + cc2] = (floatx2){hout[0], hout[1]};
      *(floatx2*)&clast[(size_t)(B0 + b) * 1024 + gc0 + cc2] = cst;
    }

    asm volatile("s_waitcnt vmcnt(0)" ::: "memory");    // h stores acked
    __syncthreads();                                    // B4: whole WG published
    if (t == 0)
      __hip_atomic_store(&flags[fb + j], s + 1, __ATOMIC_RELAXED, __HIP_MEMORY_SCOPE_AGENT);

    // out store off the critical path
    *(floatx2*)&out[((size_t)(B0 + b) * 1024 + s) * 1024 + gc0 + cc2] = (floatx2){hout[0], hout[1]};
  }

  *(floatx2*)&cstate[(size_t)(B0 + b) * 1024 + gc0 + cc2] = cst;
}

extern "C" void kernel_launch(void* const* d_in, const int* in_sizes, int n_in,
                              void* d_out, int out_size, void* d_ws, size_t ws_size,
                              hipStream_t stream)
{
  (void)in_sizes; (void)n_in; (void)out_size;
  const float* input_emb = (const float*)d_in[0];
  const float* W   = (const float*)d_in[1];
  const float* bWp = (const float*)d_in[2];
  const float* U   = (const float*)d_in[3];
  const float* bUp = (const float*)d_in[4];
  float* out   = (float*)d_out;
  float* hlast = out + (size_t)64 * 1024 * 1024;
  float* clast = hlast + 64 * 1024;

  char* base = (char*)d_ws;
  unsigned short* Wt  = (unsigned short*)base;  base += 8388608;   // [4096][1024] bf16
  unsigned short* Ut  = (unsigned short*)base;  base += 8388608;   // [4096][1024] bf16
  unsigned short* hbs = (unsigned short*)base;  base += 262144;    // [2][4][32KB] group h
  float* cstate       = (float*)base;           base += 262144;    // [64][1024] f32
  int* flags          = (int*)base;             base += 8192;      // [4][32] ints (+pad)
  size_t fixed = (size_t)(base - (char*)d_ws);
  size_t avail = ws_size > fixed ? ws_size - fixed : 0;
  int SC = 1024;
  while (SC > 8 && (size_t)SC * 655360ull > avail) SC >>= 1;
  unsigned short* Abuf = (unsigned short*)base; base += (size_t)SC * 131072;  // [SC*64][1024] bf16
  unsigned short* xpb  = (unsigned short*)base;                               // [SC*64][4096] bf16

  hipMemsetAsync(flags, 0, 8192, stream);
  hipMemsetAsync(hbs, 0, 262144, stream);       // h0 = 0 (both parities)

  k_transpose_bf16<<<dim3(16, 16, 4), 256, 0, stream>>>(W, Wt);
  k_transpose_bf16<<<dim3(16, 16, 4), 256, 0, stream>>>(U, Ut);

  int nch = 1024 / SC;
  for (int cc = 0; cc < nch; cc++){
    int s0 = cc * SC;
    k_convert_x<<<SC * 64, 256, 0, stream>>>(input_emb, Abuf, s0);
    k_gemm_xproj<<<dim3(SC / 2, 32), 256, 0, stream>>>(Abuf, Wt, bWp, bUp, xpb);
    k_lstm_rec<<<128, 256, 0, stream>>>(xpb, Ut, hbs, cstate, out, hlast, clast, flags, s0, SC);
  }
}

// Round 19
// 5998.177 us; speedup vs baseline: 2.2350x; 1.1661x over previous
//
#include <hip/hip_runtime.h>
#include <hip/hip_bf16.h>
#include <stdint.h>

// LSTM B=64 S=1024 D=1024 H=1024, gates f,i,o,g all sigmoid.
// Phase 1: xproj = x@W + bW + bU  (bf16 MFMA GEMM)
// Phase 2: persistent recurrent kernel, 128 WGs = 4 batch-groups x 32 col-WGs.
//   R19 = R18 (U pinned in AGPRs via "a" asm MFMA operands) + explicit MFMA hazard
//   nops that the compiler cannot insert around INLINEASM:
//     - "s_nop 1" before the first MFMA of each pair (VALU-write -> MFMA SrcA read)
//     - 3x "s_nop 7" after the last MFMA before VALU reads of acc (vdst -> VALU read)
//   R18's Output-1 failure (c-state drift) was exactly this missing hazard handling.
//   All else byte-identical to R12 (proven best base, 5.28ms rec).

typedef __attribute__((ext_vector_type(8))) short short8;
typedef __attribute__((ext_vector_type(4))) float floatx4;
typedef __attribute__((ext_vector_type(2))) float floatx2;

__device__ __forceinline__ unsigned short f2bf(float x){
  union { float f; unsigned int u; } v; v.f = x;
  unsigned int r = v.u + 0x7fffu + ((v.u >> 16) & 1u);
  return (unsigned short)(r >> 16);
}
__device__ __forceinline__ float bf2f(unsigned short b){
  union { unsigned int u; float f; } v; v.u = ((unsigned int)b) << 16; return v.f;
}
__device__ __forceinline__ float fsigmoid(float x){ return 1.0f / (1.0f + __expf(-x)); }
__device__ __forceinline__ float ftanh(float x){ return 1.0f - 2.0f / (1.0f + __expf(2.0f * x)); }

// ---- transpose [g][d][h] fp32 -> [g][h][d] bf16 (per-gate 1024x1024) ----
__global__ void k_transpose_bf16(const float* __restrict__ src, unsigned short* __restrict__ dst){
  __shared__ float tile[64][65];
  const int g  = blockIdx.z;
  const int d0 = blockIdx.x * 64;
  const int h0 = blockIdx.y * 64;
  const int t  = threadIdx.x;
  const float* s    = src + ((size_t)g << 20);
  unsigned short* o = dst + ((size_t)g << 20);
  #pragma unroll
  for (int i = 0; i < 16; i++){
    int e = i * 256 + t;
    int r = e >> 6, c = e & 63;
    tile[r][c] = s[(size_t)(d0 + r) * 1024 + (h0 + c)];
  }
  __syncthreads();
  #pragma unroll
  for (int i = 0; i < 16; i++){
    int e = i * 256 + t;
    int a = e >> 6, bb = e & 63;
    o[(size_t)(h0 + a) * 1024 + (d0 + bb)] = f2bf(tile[bb][a]);
  }
}

// ---- convert input chunk (B,S,D) fp32 -> Abuf[(sl*64+b)][d] bf16 ----
__global__ void k_convert_x(const float* __restrict__ inp, unsigned short* __restrict__ abuf, int s0){
  int idx = blockIdx.x * 256 + threadIdx.x;
  int e = idx * 4;
  int r = e >> 10, d = e & 1023;
  int b = r & 63, sl = r >> 6;
  floatx4 v = *(const floatx4*)(inp + ((size_t)(b * 1024 + (s0 + sl)) * 1024 + d));
  unsigned long long pk = (unsigned long long)f2bf(v[0])
                        | ((unsigned long long)f2bf(v[1]) << 16)
                        | ((unsigned long long)f2bf(v[2]) << 32)
                        | ((unsigned long long)f2bf(v[3]) << 48);
  *(unsigned long long*)(abuf + (size_t)r * 1024 + d) = pk;
}

// ---- xproj GEMM: C[M][4096] = A[M][1024] @ Bt^T + (bW+bU), bf16 out ----
__global__ void __launch_bounds__(256) k_gemm_xproj(
    const unsigned short* __restrict__ A,
    const unsigned short* __restrict__ Bt,
    const float* __restrict__ bW,
    const float* __restrict__ bU,
    unsigned short* __restrict__ Cc)
{
  __shared__ unsigned short As[2][128][64];
  __shared__ unsigned short Bs[2][128][64];
  const int t = threadIdx.x;
  const int w = t >> 6;
  const int lane = t & 63;
  const int m0 = blockIdx.x * 128;
  const int n0 = blockIdx.y * 128;
  floatx4 acc[4][4];
  #pragma unroll
  for (int i = 0; i < 4; i++)
    #pragma unroll
    for (int j = 0; j < 4; j++)
      acc[i][j] = (floatx4){0.f, 0.f, 0.f, 0.f};

  auto stage = [&](int bufi, int kt){
    #pragma unroll
    for (int i = 0; i < 4; i++){
      int chunk = i * 256 + t;
      int r = chunk >> 3, j = chunk & 7;
      int js = j ^ (r & 7);
      __builtin_amdgcn_global_load_lds(
        (const __attribute__((address_space(1))) unsigned int*)(A + (size_t)(m0 + r) * 1024 + kt * 64 + js * 8),
        (__attribute__((address_space(3))) unsigned int*)(&As[bufi][0][0] + (i * 256 + w * 64) * 8), 16, 0, 0);
    }
    #pragma unroll
    for (int i = 0; i < 4; i++){
      int chunk = i * 256 + t;
      int r = chunk >> 3, j = chunk & 7;
      int js = j ^ (r & 7);
      __builtin_amdgcn_global_load_lds(
        (const __attribute__((address_space(1))) unsigned int*)(Bt + (size_t)(n0 + r) * 1024 + kt * 64 + js * 8),
        (__attribute__((address_space(3))) unsigned int*)(&Bs[bufi][0][0] + (i * 256 + w * 64) * 8), 16, 0, 0);
    }
  };

  auto compute = [&](int bufi){
    const int mi0 = (w >> 1) * 64;
    const int ni0 = (w & 1) * 64;
    #pragma unroll
    for (int kc = 0; kc < 2; kc++){
      short8 af[4], bfr[4];
      #pragma unroll
      for (int mi = 0; mi < 4; mi++){
        int row = mi0 + mi * 16 + (lane & 15);
        int j = kc * 4 + (lane >> 4);
        af[mi] = *(const short8*)&As[bufi][row][(j ^ (row & 7)) * 8];
      }
      #pragma unroll
      for (int ni = 0; ni < 4; ni++){
        int row = ni0 + ni * 16 + (lane & 15);
        int j = kc * 4 + (lane >> 4);
        bfr[ni] = *(const short8*)&Bs[bufi][row][(j ^ (row & 7)) * 8];
      }
      #pragma unroll
      for (int mi = 0; mi < 4; mi++)
        #pragma unroll
        for (int ni = 0; ni < 4; ni++)
          acc[mi][ni] = __builtin_amdgcn_mfma_f32_16x16x32_bf16(af[mi], bfr[ni], acc[mi][ni], 0, 0, 0);
    }
  };

  stage(0, 0);
  int buf = 0;
  for (int kt = 0; kt < 16; kt++){
    __syncthreads();
    if (kt < 15) stage(buf ^ 1, kt + 1);
    compute(buf);
    buf ^= 1;
  }

  {
    const int mi0 = (w >> 1) * 64;
    const int ni0 = (w & 1) * 64;
    #pragma unroll
    for (int ni = 0; ni < 4; ni++){
      int col = n0 + ni0 + ni * 16 + (lane & 15);
      float bias = bW[col] + bU[col];
      #pragma unroll
      for (int mi = 0; mi < 4; mi++){
        int mrow = m0 + mi0 + mi * 16 + (lane >> 4) * 4;
        #pragma unroll
        for (int r = 0; r < 4; r++)
          Cc[(size_t)(mrow + r) * 4096 + col] = f2bf(acc[mi][ni][r] + bias);
      }
    }
  }
}

// ---- persistent recurrent kernel: 128 WGs = 4 groups(16 batches) x 32 col-WGs ----
// Group buffer (per parity, per group): 32KB = 32 subtiles x 1KB. Subtile kc holds the
// MFMA A-frag for k in [kc*32,kc*32+32): element (r, k=kc*32+jj*8+e) at byte
// (jj*16 + r)*16 + e*2, r = batch row 0..15. Consumer lane l reads bytes [l*16,l*16+16)
// of each subtile straight into regs via AGENT-scope atomic loads.
// Producer thread (b,cc2): one 4B AGENT-scope atomic store. flags[g*32+j] per WG.
// U fragments live in AGPRs ("a" asm operands) with explicit hazard s_nops.
__global__ void __launch_bounds__(256, 1) k_lstm_rec(
    const unsigned short* __restrict__ xp,   // [SC*64][4096] bf16
    const unsigned short* __restrict__ Ut,   // [4096][1024] bf16 (gate-major rows)
    unsigned short* hbs,                     // [2][4][32768B] h group buffers
    float* cstate,                           // [64][1024]
    float* __restrict__ out,                 // (B,S,H) fp32
    float* __restrict__ hlast,
    float* __restrict__ clast,
    int* flags,                              // [4][32] ints (group-contiguous lines)
    int s_base, int SC)
{
  const int t = threadIdx.x;
  const int w = t >> 6;            // wave = gate
  const int lane = t & 63;
  const int wgid = blockIdx.x;
  const int g  = wgid & 3;         // batch group: batches 16g..16g+15
  const int j  = wgid >> 2;        // col-slice: h-cols [j*32, j*32+32)
  const int B0 = g * 16;
  const int gc0 = j * 32;

  __shared__ float glds[4][16][33];          // gate exchange [gate][batch][col]

  // U: wave w = gate w, cols gc0..gc0+31 (two 16-col N-tiles), full K=1024.
  // 64 short8 frags = 256 regs, pinned in AGPRs by the "a" constraint below.
  short8 bfrag0[32], bfrag1[32];
  {
    const unsigned short* bp0 = Ut + (size_t)(w * 1024 + gc0 + (lane & 15)) * 1024 + (lane >> 4) * 8;
    const unsigned short* bp1 = bp0 + (size_t)16 * 1024;
    #pragma unroll
    for (int kc = 0; kc < 32; kc++){
      bfrag0[kc] = *(const short8*)(bp0 + kc * 32);
      bfrag1[kc] = *(const short8*)(bp1 + kc * 32);
    }
  }

  const int b   = t >> 4;          // local batch 0..15 owned in epilogue
  const int cc2 = (t & 15) * 2;    // 2 local h-cols owned: cc2, cc2+1
  floatx2 cst;
  if (s_base == 0) cst = (floatx2){0.f, 0.f};
  else             cst = *(const floatx2*)&cstate[(size_t)(B0 + b) * 1024 + gc0 + cc2];

  int bail = 20000000;
  const int fb = g * 32;

  for (int sl = 0; sl < SC; sl++){
    const int s = s_base + sl;
    const int p = s & 1;

    // xp prefetch (independent of h): 2 cols per gate as one 4B load
    unsigned int xu[4];
    {
      const unsigned short* xr = xp + ((size_t)(sl * 64 + B0 + b)) * 4096 + gc0 + cc2;
      #pragma unroll
      for (int gg = 0; gg < 4; gg++) xu[gg] = *(const unsigned int*)(xr + gg * 1024);
    }
    __builtin_amdgcn_sched_barrier(0);

    const char* gsrc = (const char*)hbs + ((size_t)p * 4 + g) * 32768;
    floatx4 acc0 = (floatx4){0.f,0.f,0.f,0.f};
    floatx4 acc1 = (floatx4){0.f,0.f,0.f,0.f};

    // per-wave per-chunk wait: only the 8 producers of chunk c gate chunk c's loads
    auto wait_chunk = [&](int c){
      if (s == 0) return;
      const int* fp2 = &flags[fb + c * 8 + (lane & 7)];
      while (true){
        int v = __hip_atomic_load(fp2, __ATOMIC_RELAXED, __HIP_MEMORY_SCOPE_AGENT);
        if (__all(v >= s)) break;
        __builtin_amdgcn_s_sleep(1);
        if (--bail < 0) break;
      }
    };

    unsigned long long loA[8], hiA[8], loB[8], hiB[8];
    auto issue8 = [&](unsigned long long (&lo)[8], unsigned long long (&hi)[8], int ch){
      #pragma unroll
      for (int i = 0; i < 8; i++){
        const unsigned long long* sp2 = (const unsigned long long*)(gsrc + (ch * 8 + i) * 1024 + lane * 16);
        lo[i] = __hip_atomic_load(sp2,     __ATOMIC_RELAXED, __HIP_MEMORY_SCOPE_AGENT);
        hi[i] = __hip_atomic_load(sp2 + 1, __ATOMIC_RELAXED, __HIP_MEMORY_SCOPE_AGENT);
      }
    };
    auto crunch8 = [&](unsigned long long (&lo)[8], unsigned long long (&hi)[8], int ch){
      #pragma unroll
      for (int i = 0; i < 8; i++){
        union { unsigned long long q[2]; short8 v; } u;
        u.q[0] = lo[i]; u.q[1] = hi[i];
        // s_nop 1 covers VALU-write -> MFMA SrcA-read hazard (asm is opaque to
        // the compiler's MAI hazard recognizer). B operand pinned in AGPRs.
        asm volatile("s_nop 1\n\tv_mfma_f32_16x16x32_bf16 %0, %1, %2, %0"
                     : "+v"(acc0) : "v"(u.v), "a"(bfrag0[ch * 8 + i]));
        asm volatile("v_mfma_f32_16x16x32_bf16 %0, %1, %2, %0"
                     : "+v"(acc1) : "v"(u.v), "a"(bfrag1[ch * 8 + i]));
      }
    };
    wait_chunk(0);
    issue8(loA, hiA, 0);
    wait_chunk(1);
    issue8(loB, hiB, 1);
    crunch8(loA, hiA, 0);
    wait_chunk(2);
    issue8(loA, hiA, 2);
    crunch8(loB, hiB, 1);
    wait_chunk(3);
    issue8(loB, hiB, 3);
    crunch8(loA, hiA, 2);
    crunch8(loB, hiB, 3);
    // MFMA vdst -> VALU read hazard barrier (compiler can't see asm MFMAs)
    asm volatile("s_nop 7\n\ts_nop 7\n\ts_nop 7" ::: "memory");

    // publish gate values (all 16 rows real). C: row=(l>>4)*4+reg, col=l&15.
    {
      const int r0 = (lane >> 4) * 4;
      const int cl = lane & 15;
      #pragma unroll
      for (int r = 0; r < 4; r++){
        glds[w][r0 + r][cl]      = acc0[r];
        glds[w][r0 + r][16 + cl] = acc1[r];
      }
    }
    __syncthreads();                                    // B3

    // epilogue: thread owns (b, cc2) and (b, cc2+1)
    float hout[2];
    #pragma unroll
    for (int d = 0; d < 2; d++){
      float fv = fsigmoid(glds[0][b][cc2 + d] + bf2f((unsigned short)(xu[0] >> (16 * d))));
      float iv = fsigmoid(glds[1][b][cc2 + d] + bf2f((unsigned short)(xu[1] >> (16 * d))));
      float ov = fsigmoid(glds[2][b][cc2 + d] + bf2f((unsigned short)(xu[2] >> (16 * d))));
      float gv = fsigmoid(glds[3][b][cc2 + d] + bf2f((unsigned short)(xu[3] >> (16 * d))));  // sigmoid, not tanh
      float cv = fv * cst[d] + iv * gv;
      cst[d] = cv;
      hout[d] = ov * ftanh(cv);
    }

    // publish h: per-thread 4B AGENT-scope atomic store into subtile j.
    {
      unsigned int hv = (unsigned int)f2bf(hout[0]) | ((unsigned int)f2bf(hout[1]) << 16);
      unsigned int* dst = (unsigned int*)((char*)hbs + ((size_t)(p ^ 1) * 4 + g) * 32768 + j * 1024
                + (((cc2 >> 3) * 16 + b) << 4) + ((cc2 & 7) << 1));
      __hip_atomic_store(dst, hv, __ATOMIC_RELAXED, __HIP_MEMORY_SCOPE_AGENT);
    }

    if (s == 1023){
      *(floatx2*)&hlast[(size_t)(B0 + b) * 1024 + gc0 + cc2] = (floatx2){hout[0], hout[1]};
      *(floatx2*)&clast[(size_t)(B0 + b) * 1024 + gc0 + cc2] = cst;
    }

    asm volatile("s_waitcnt vmcnt(0)" ::: "memory");    // h stores acked
    __syncthreads();                                    // B4: all waves drained
    if (t == 0)
      __hip_atomic_store(&flags[fb + j], s + 1, __ATOMIC_RELAXED, __HIP_MEMORY_SCOPE_AGENT);

    // out store off the critical path
    *(floatx2*)&out[((size_t)(B0 + b) * 1024 + s) * 1024 + gc0 + cc2] = (floatx2){hout[0], hout[1]};
  }

  *(floatx2*)&cstate[(size_t)(B0 + b) * 1024 + gc0 + cc2] = cst;
}

extern "C" void kernel_launch(void* const* d_in, const int* in_sizes, int n_in,
                              void* d_out, int out_size, void* d_ws, size_t ws_size,
                              hipStream_t stream)
{
  (void)in_sizes; (void)n_in; (void)out_size;
  const float* input_emb = (const float*)d_in[0];
  const float* W   = (const float*)d_in[1];
  const float* bWp = (const float*)d_in[2];
  const float* U   = (const float*)d_in[3];
  const float* bUp = (const float*)d_in[4];
  float* out   = (float*)d_out;
  float* hlast = out + (size_t)64 * 1024 * 1024;
  float* clast = hlast + 64 * 1024;

  char* base = (char*)d_ws;
  unsigned short* Wt  = (unsigned short*)base;  base += 8388608;   // [4096][1024] bf16
  unsigned short* Ut  = (unsigned short*)base;  base += 8388608;   // [4096][1024] bf16
  unsigned short* hbs = (unsigned short*)base;  base += 262144;    // [2][4][32KB] group h
  float* cstate       = (float*)base;           base += 262144;    // [64][1024] f32
  int* flags          = (int*)base;             base += 8192;      // [4][32] ints (+pad)
  size_t fixed = (size_t)(base - (char*)d_ws);
  size_t avail = ws_size > fixed ? ws_size - fixed : 0;
  int SC = 1024;
  while (SC > 8 && (size_t)SC * 655360ull > avail) SC >>= 1;
  unsigned short* Abuf = (unsigned short*)base; base += (size_t)SC * 131072;  // [SC*64][1024] bf16
  unsigned short* xpb  = (unsigned short*)base;                               // [SC*64][4096] bf16

  hipMemsetAsync(flags, 0, 8192, stream);
  hipMemsetAsync(hbs, 0, 262144, stream);       // h0 = 0 (both parities)

  k_transpose_bf16<<<dim3(16, 16, 4), 256, 0, stream>>>(W, Wt);
  k_transpose_bf16<<<dim3(16, 16, 4), 256, 0, stream>>>(U, Ut);

  int nch = 1024 / SC;
  for (int cc = 0; cc < nch; cc++){
    int s0 = cc * SC;
    k_convert_x<<<SC * 64, 256, 0, stream>>>(input_emb, Abuf, s0);
    k_gemm_xproj<<<dim3(SC / 2, 32), 256, 0, stream>>>(Abuf, Wt, bWp, bUp, xpb);
    k_lstm_rec<<<128, 256, 0, stream>>>(xpb, Ut, hbs, cstate, out, hlast, clast, flags, s0, SC);
  }
}

// Round 20
// 5269.690 us; speedup vs baseline: 2.5440x; 1.1382x over previous
//
#include <hip/hip_runtime.h>
#include <hip/hip_bf16.h>
#include <stdint.h>

// LSTM B=64 S=1024 D=1024 H=1024, gates f,i,o,g all sigmoid.
// R20 = R19 rec (AGPR-pinned U, 4.92ms) + producer/consumer FUSION:
//   one 256-WG kernel: WGs 0-127 = persistent xproj GEMM producers (16384 tiles,
//   m-tile-major), WGs 128-255 = the R19 recurrence. Rec gates step sl on
//   mcnt[sl/2]==32 (m-tile complete). Hides the ~0.6ms serial GEMM under the
//   4.9ms recurrence. Producer release: vmcnt + syncthreads + t0 agent fence + add.

typedef __attribute__((ext_vector_type(8))) short short8;
typedef __attribute__((ext_vector_type(4))) float floatx4;
typedef __attribute__((ext_vector_type(2))) float floatx2;

__device__ __forceinline__ unsigned short f2bf(float x){
  union { float f; unsigned int u; } v; v.f = x;
  unsigned int r = v.u + 0x7fffu + ((v.u >> 16) & 1u);
  return (unsigned short)(r >> 16);
}
__device__ __forceinline__ float bf2f(unsigned short b){
  union { unsigned int u; float f; } v; v.u = ((unsigned int)b) << 16; return v.f;
}
__device__ __forceinline__ float fsigmoid(float x){ return 1.0f / (1.0f + __expf(-x)); }
__device__ __forceinline__ float ftanh(float x){ return 1.0f - 2.0f / (1.0f + __expf(2.0f * x)); }

// ---- transpose [g][d][h] fp32 -> [g][h][d] bf16 (per-gate 1024x1024) ----
__global__ void k_transpose_bf16(const float* __restrict__ src, unsigned short* __restrict__ dst){
  __shared__ float tile[64][65];
  const int g  = blockIdx.z;
  const int d0 = blockIdx.x * 64;
  const int h0 = blockIdx.y * 64;
  const int t  = threadIdx.x;
  const float* s    = src + ((size_t)g << 20);
  unsigned short* o = dst + ((size_t)g << 20);
  #pragma unroll
  for (int i = 0; i < 16; i++){
    int e = i * 256 + t;
    int r = e >> 6, c = e & 63;
    tile[r][c] = s[(size_t)(d0 + r) * 1024 + (h0 + c)];
  }
  __syncthreads();
  #pragma unroll
  for (int i = 0; i < 16; i++){
    int e = i * 256 + t;
    int a = e >> 6, bb = e & 63;
    o[(size_t)(h0 + a) * 1024 + (d0 + bb)] = f2bf(tile[bb][a]);
  }
}

// ---- convert input chunk (B,S,D) fp32 -> Abuf[(sl*64+b)][d] bf16 ----
__global__ void k_convert_x(const float* __restrict__ inp, unsigned short* __restrict__ abuf, int s0){
  int idx = blockIdx.x * 256 + threadIdx.x;
  int e = idx * 4;
  int r = e >> 10, d = e & 1023;
  int b = r & 63, sl = r >> 6;
  floatx4 v = *(const floatx4*)(inp + ((size_t)(b * 1024 + (s0 + sl)) * 1024 + d));
  unsigned long long pk = (unsigned long long)f2bf(v[0])
                        | ((unsigned long long)f2bf(v[1]) << 16)
                        | ((unsigned long long)f2bf(v[2]) << 32)
                        | ((unsigned long long)f2bf(v[3]) << 48);
  *(unsigned long long*)(abuf + (size_t)r * 1024 + d) = pk;
}

// ---- fused producer/consumer kernel ----
// WGs 0-127: persistent xproj GEMM producers. WGs 128-255: recurrence (R19 body).
// xp layout [SC*64][4096]; m-tile mt covers rows [mt*128, mt*128+128) = steps 2mt,2mt+1.
// mcnt[mt] counts completed n-tiles (32 = ready). hbs/flags as in R12/R19.
__global__ void __launch_bounds__(256, 1) k_fused(
    const unsigned short* __restrict__ Abuf, // [SC*64][1024] bf16
    const unsigned short* __restrict__ Wt,   // [4096][1024] bf16
    const float* __restrict__ bW,
    const float* __restrict__ bU,
    unsigned short* __restrict__ xp,         // [SC*64][4096] bf16
    const unsigned short* __restrict__ Ut,   // [4096][1024] bf16
    unsigned short* hbs,                     // [2][4][32768B]
    float* cstate,
    float* __restrict__ out,
    float* __restrict__ hlast,
    float* __restrict__ clast,
    int* flags,                              // [4][32]
    int* mcnt,                               // [SC/2] m-tile counters (zeroed)
    int s_base, int SC)
{
  union Smem {
    struct { unsigned short As[2][128][64]; unsigned short Bs[2][128][64]; } g;
    float glds[4][16][33];
  };
  __shared__ Smem sm;

  const int t = threadIdx.x;

  if (blockIdx.x < 128){
    // ================= producer: xproj GEMM =================
    const int pwg = blockIdx.x;
    const int w = t >> 6;
    const int lane = t & 63;
    const int ntiles = SC * 16;              // (SC*64/128) m-tiles * 32 n-tiles

    for (int tile = pwg; tile < ntiles; tile += 128){
      const int mt = tile >> 5, nt = tile & 31;
      const int m0 = mt * 128, n0 = nt * 128;

      floatx4 acc[4][4];
      #pragma unroll
      for (int i = 0; i < 4; i++)
        #pragma unroll
        for (int jj = 0; jj < 4; jj++)
          acc[i][jj] = (floatx4){0.f, 0.f, 0.f, 0.f};

      auto stage = [&](int bufi, int kt){
        #pragma unroll
        for (int i = 0; i < 4; i++){
          int chunk = i * 256 + t;
          int r = chunk >> 3, jx = chunk & 7;
          int js = jx ^ (r & 7);
          __builtin_amdgcn_global_load_lds(
            (const __attribute__((address_space(1))) unsigned int*)(Abuf + (size_t)(m0 + r) * 1024 + kt * 64 + js * 8),
            (__attribute__((address_space(3))) unsigned int*)(&sm.g.As[bufi][0][0] + (i * 256 + w * 64) * 8), 16, 0, 0);
        }
        #pragma unroll
        for (int i = 0; i < 4; i++){
          int chunk = i * 256 + t;
          int r = chunk >> 3, jx = chunk & 7;
          int js = jx ^ (r & 7);
          __builtin_amdgcn_global_load_lds(
            (const __attribute__((address_space(1))) unsigned int*)(Wt + (size_t)(n0 + r) * 1024 + kt * 64 + js * 8),
            (__attribute__((address_space(3))) unsigned int*)(&sm.g.Bs[bufi][0][0] + (i * 256 + w * 64) * 8), 16, 0, 0);
        }
      };

      auto compute = [&](int bufi){
        const int mi0 = (w >> 1) * 64;
        const int ni0 = (w & 1) * 64;
        #pragma unroll
        for (int kc = 0; kc < 2; kc++){
          short8 af[4], bfr[4];
          #pragma unroll
          for (int mi = 0; mi < 4; mi++){
            int row = mi0 + mi * 16 + (lane & 15);
            int jx = kc * 4 + (lane >> 4);
            af[mi] = *(const short8*)&sm.g.As[bufi][row][(jx ^ (row & 7)) * 8];
          }
          #pragma unroll
          for (int ni = 0; ni < 4; ni++){
            int row = ni0 + ni * 16 + (lane & 15);
            int jx = kc * 4 + (lane >> 4);
            bfr[ni] = *(const short8*)&sm.g.Bs[bufi][row][(jx ^ (row & 7)) * 8];
          }
          #pragma unroll
          for (int mi = 0; mi < 4; mi++)
            #pragma unroll
            for (int ni = 0; ni < 4; ni++)
              acc[mi][ni] = __builtin_amdgcn_mfma_f32_16x16x32_bf16(af[mi], bfr[ni], acc[mi][ni], 0, 0, 0);
        }
      };

      stage(0, 0);
      int buf = 0;
      for (int kt = 0; kt < 16; kt++){
        __syncthreads();
        if (kt < 15) stage(buf ^ 1, kt + 1);
        compute(buf);
        buf ^= 1;
      }

      {
        const int mi0 = (w >> 1) * 64;
        const int ni0 = (w & 1) * 64;
        #pragma unroll
        for (int ni = 0; ni < 4; ni++){
          int col = n0 + ni0 + ni * 16 + (lane & 15);
          float bias = bW[col] + bU[col];
          #pragma unroll
          for (int mi = 0; mi < 4; mi++){
            int mrow = m0 + mi0 + mi * 16 + (lane >> 4) * 4;
            #pragma unroll
            for (int r = 0; r < 4; r++)
              xp[(size_t)(mrow + r) * 4096 + col] = f2bf(acc[mi][ni][r] + bias);
          }
        }
      }

      // release this tile: all waves drain, then t0 publishes to L3 + counts
      asm volatile("s_waitcnt vmcnt(0)" ::: "memory");
      __syncthreads();
      if (t == 0){
        __builtin_amdgcn_fence(__ATOMIC_RELEASE, "agent");
        __hip_atomic_fetch_add(&mcnt[mt], 1, __ATOMIC_RELAXED, __HIP_MEMORY_SCOPE_AGENT);
      }
      __syncthreads();
    }
    return;
  }

  // ================= consumer: recurrence (R19 body) =================
  const int w = t >> 6;            // wave = gate
  const int lane = t & 63;
  const int wgid = blockIdx.x - 128;
  const int g  = wgid & 3;         // batch group: batches 16g..16g+15
  const int j  = wgid >> 2;        // col-slice: h-cols [j*32, j*32+32)
  const int B0 = g * 16;
  const int gc0 = j * 32;

  short8 bfrag0[32], bfrag1[32];
  {
    const unsigned short* bp0 = Ut + (size_t)(w * 1024 + gc0 + (lane & 15)) * 1024 + (lane >> 4) * 8;
    const unsigned short* bp1 = bp0 + (size_t)16 * 1024;
    #pragma unroll
    for (int kc = 0; kc < 32; kc++){
      bfrag0[kc] = *(const short8*)(bp0 + kc * 32);
      bfrag1[kc] = *(const short8*)(bp1 + kc * 32);
    }
  }

  const int b   = t >> 4;
  const int cc2 = (t & 15) * 2;
  floatx2 cst;
  if (s_base == 0) cst = (floatx2){0.f, 0.f};
  else             cst = *(const floatx2*)&cstate[(size_t)(B0 + b) * 1024 + gc0 + cc2];

  int bail = 20000000;
  const int fb = g * 32;

  for (int sl = 0; sl < SC; sl++){
    const int s = s_base + sl;
    const int p = s & 1;

    // gate on xproj m-tile (every other step); uniform-address poll per wave
    if (!(sl & 1)){
      const int mt = sl >> 1;
      while (true){
        int v = __hip_atomic_load(&mcnt[mt], __ATOMIC_RELAXED, __HIP_MEMORY_SCOPE_AGENT);
        if (__all(v >= 32)) break;
        __builtin_amdgcn_s_sleep(2);
        if (--bail < 0) break;
      }
      asm volatile("" ::: "memory");
    }

    // xp prefetch (now gated): 2 cols per gate as one 4B load
    unsigned int xu[4];
    {
      const unsigned short* xr = xp + ((size_t)(sl * 64 + B0 + b)) * 4096 + gc0 + cc2;
      #pragma unroll
      for (int gg = 0; gg < 4; gg++) xu[gg] = *(const unsigned int*)(xr + gg * 1024);
    }
    __builtin_amdgcn_sched_barrier(0);

    const char* gsrc = (const char*)hbs + ((size_t)p * 4 + g) * 32768;
    floatx4 acc0 = (floatx4){0.f,0.f,0.f,0.f};
    floatx4 acc1 = (floatx4){0.f,0.f,0.f,0.f};

    auto wait_chunk = [&](int c){
      if (s == 0) return;
      const int* fp2 = &flags[fb + c * 8 + (lane & 7)];
      while (true){
        int v = __hip_atomic_load(fp2, __ATOMIC_RELAXED, __HIP_MEMORY_SCOPE_AGENT);
        if (__all(v >= s)) break;
        __builtin_amdgcn_s_sleep(1);
        if (--bail < 0) break;
      }
    };

    unsigned long long loA[8], hiA[8], loB[8], hiB[8];
    auto issue8 = [&](unsigned long long (&lo)[8], unsigned long long (&hi)[8], int ch){
      #pragma unroll
      for (int i = 0; i < 8; i++){
        const unsigned long long* sp2 = (const unsigned long long*)(gsrc + (ch * 8 + i) * 1024 + lane * 16);
        lo[i] = __hip_atomic_load(sp2,     __ATOMIC_RELAXED, __HIP_MEMORY_SCOPE_AGENT);
        hi[i] = __hip_atomic_load(sp2 + 1, __ATOMIC_RELAXED, __HIP_MEMORY_SCOPE_AGENT);
      }
    };
    auto crunch8 = [&](unsigned long long (&lo)[8], unsigned long long (&hi)[8], int ch){
      #pragma unroll
      for (int i = 0; i < 8; i++){
        union { unsigned long long q[2]; short8 v; } u;
        u.q[0] = lo[i]; u.q[1] = hi[i];
        asm volatile("s_nop 1\n\tv_mfma_f32_16x16x32_bf16 %0, %1, %2, %0"
                     : "+v"(acc0) : "v"(u.v), "a"(bfrag0[ch * 8 + i]));
        asm volatile("v_mfma_f32_16x16x32_bf16 %0, %1, %2, %0"
                     : "+v"(acc1) : "v"(u.v), "a"(bfrag1[ch * 8 + i]));
      }
    };
    wait_chunk(0);
    issue8(loA, hiA, 0);
    wait_chunk(1);
    issue8(loB, hiB, 1);
    crunch8(loA, hiA, 0);
    wait_chunk(2);
    issue8(loA, hiA, 2);
    crunch8(loB, hiB, 1);
    wait_chunk(3);
    issue8(loB, hiB, 3);
    crunch8(loA, hiA, 2);
    crunch8(loB, hiB, 3);
    asm volatile("s_nop 7\n\ts_nop 7\n\ts_nop 7" ::: "memory");

    {
      const int r0 = (lane >> 4) * 4;
      const int cl = lane & 15;
      #pragma unroll
      for (int r = 0; r < 4; r++){
        sm.glds[w][r0 + r][cl]      = acc0[r];
        sm.glds[w][r0 + r][16 + cl] = acc1[r];
      }
    }
    __syncthreads();                                    // B3

    float hout[2];
    #pragma unroll
    for (int d = 0; d < 2; d++){
      float fv = fsigmoid(sm.glds[0][b][cc2 + d] + bf2f((unsigned short)(xu[0] >> (16 * d))));
      float iv = fsigmoid(sm.glds[1][b][cc2 + d] + bf2f((unsigned short)(xu[1] >> (16 * d))));
      float ov = fsigmoid(sm.glds[2][b][cc2 + d] + bf2f((unsigned short)(xu[2] >> (16 * d))));
      float gv = fsigmoid(sm.glds[3][b][cc2 + d] + bf2f((unsigned short)(xu[3] >> (16 * d))));  // sigmoid
      float cv = fv * cst[d] + iv * gv;
      cst[d] = cv;
      hout[d] = ov * ftanh(cv);
    }

    {
      unsigned int hv = (unsigned int)f2bf(hout[0]) | ((unsigned int)f2bf(hout[1]) << 16);
      unsigned int* dst = (unsigned int*)((char*)hbs + ((size_t)(p ^ 1) * 4 + g) * 32768 + j * 1024
                + (((cc2 >> 3) * 16 + b) << 4) + ((cc2 & 7) << 1));
      __hip_atomic_store(dst, hv, __ATOMIC_RELAXED, __HIP_MEMORY_SCOPE_AGENT);
    }

    if (s == 1023){
      *(floatx2*)&hlast[(size_t)(B0 + b) * 1024 + gc0 + cc2] = (floatx2){hout[0], hout[1]};
      *(floatx2*)&clast[(size_t)(B0 + b) * 1024 + gc0 + cc2] = cst;
    }

    asm volatile("s_waitcnt vmcnt(0)" ::: "memory");
    __syncthreads();                                    // B4
    if (t == 0)
      __hip_atomic_store(&flags[fb + j], s + 1, __ATOMIC_RELAXED, __HIP_MEMORY_SCOPE_AGENT);

    *(floatx2*)&out[((size_t)(B0 + b) * 1024 + s) * 1024 + gc0 + cc2] = (floatx2){hout[0], hout[1]};
  }

  *(floatx2*)&cstate[(size_t)(B0 + b) * 1024 + gc0 + cc2] = cst;
}

extern "C" void kernel_launch(void* const* d_in, const int* in_sizes, int n_in,
                              void* d_out, int out_size, void* d_ws, size_t ws_size,
                              hipStream_t stream)
{
  (void)in_sizes; (void)n_in; (void)out_size;
  const float* input_emb = (const float*)d_in[0];
  const float* W   = (const float*)d_in[1];
  const float* bWp = (const float*)d_in[2];
  const float* U   = (const float*)d_in[3];
  const float* bUp = (const float*)d_in[4];
  float* out   = (float*)d_out;
  float* hlast = out + (size_t)64 * 1024 * 1024;
  float* clast = hlast + 64 * 1024;

  char* base = (char*)d_ws;
  unsigned short* Wt  = (unsigned short*)base;  base += 8388608;   // [4096][1024] bf16
  unsigned short* Ut  = (unsigned short*)base;  base += 8388608;   // [4096][1024] bf16
  unsigned short* hbs = (unsigned short*)base;  base += 262144;    // [2][4][32KB] group h
  float* cstate       = (float*)base;           base += 262144;    // [64][1024] f32
  int* flags          = (int*)base;             base += 8192;      // [4][32] ints (+pad)
  int* mcnt           = (int*)base;             base += 4096;      // [SC/2] m-tile counters
  size_t fixed = (size_t)(base - (char*)d_ws);
  size_t avail = ws_size > fixed ? ws_size - fixed : 0;
  int SC = 1024;
  while (SC > 8 && (size_t)SC * 655360ull > avail) SC >>= 1;
  unsigned short* Abuf = (unsigned short*)base; base += (size_t)SC * 131072;  // [SC*64][1024] bf16
  unsigned short* xpb  = (unsigned short*)base;                               // [SC*64][4096] bf16

  hipMemsetAsync(flags, 0, 8192, stream);
  hipMemsetAsync(hbs, 0, 262144, stream);       // h0 = 0 (both parities)

  k_transpose_bf16<<<dim3(16, 16, 4), 256, 0, stream>>>(W, Wt);
  k_transpose_bf16<<<dim3(16, 16, 4), 256, 0, stream>>>(U, Ut);

  int nch = 1024 / SC;
  for (int cc = 0; cc < nch; cc++){
    int s0 = cc * SC;
    hipMemsetAsync(mcnt, 0, 4096, stream);
    k_convert_x<<<SC * 64, 256, 0, stream>>>(input_emb, Abuf, s0);
    k_fused<<<256, 256, 0, stream>>>(Abuf, Wt, bWp, bUp, xpb, Ut, hbs, cstate,
                                     out, hlast, clast, flags, mcnt, s0, SC);
  }
}